// Round 1
// baseline (542.221 us; speedup 1.0000x reference)
//
#include <hip/hip_runtime.h>
#include <hip/hip_bf16.h>
#include <math.h>

typedef unsigned short u16;
typedef unsigned int u32;
typedef short s8v __attribute__((ext_vector_type(8)));   // 8 x bf16 bits (4 VGPRs)
typedef float f4v __attribute__((ext_vector_type(4)));   // 16x16 MFMA accumulator
typedef float f16v __attribute__((ext_vector_type(16))); // 32x32 MFMA accumulator
typedef u32 u4v __attribute__((ext_vector_type(4)));

#define D_MODEL 1024
#define DIMFF   4096
#define SEQ     2048
#define TOKENS  8192   // B*T

// 0.125 (1/sqrt(dh)) * log2(e): folded into Q at the QKV epilogue
#define QSCALE 0.18033688011112042f

static __device__ __forceinline__ u16 f2bf(float f) {
    unsigned int u = __builtin_bit_cast(unsigned int, f);
    unsigned int lsb = (u >> 16) & 1u;
    u += 0x7fffu + lsb;                 // round-to-nearest-even
    return (u16)(u >> 16);
}

static __device__ __forceinline__ float gelu_fast(float z) {
    float z2 = z * z;
    float p  = fmaf(z2, -0.1029472255f, -2.3021867892f);  // -2*log2e*sqrt(2/pi)*{0.044715, 1}
    float e  = __builtin_amdgcn_exp2f(z * p);
    return z * __builtin_amdgcn_rcpf(1.0f + e);
}

// async global->LDS, 16B per lane; lds dest = wave-uniform base + lane*16
static __device__ __forceinline__ void gl2lds16(const u16* g, u16* l) {
    __builtin_amdgcn_global_load_lds(
        (__attribute__((address_space(1))) void*)(void*)g,
        (__attribute__((address_space(3))) void*)l, 16, 0, 0);
}

// raw barrier (no compiler vmcnt(0) drain like __syncthreads) + motion fences
static __device__ __forceinline__ void bar() {
    __builtin_amdgcn_sched_barrier(0);
    asm volatile("" ::: "memory");
    __builtin_amdgcn_s_barrier();
    asm volatile("" ::: "memory");
    __builtin_amdgcn_sched_barrier(0);
}

template<int N> static __device__ __forceinline__ void vwait() {
    if constexpr (N == 8)       asm volatile("s_waitcnt vmcnt(8)" ::: "memory");
    else if constexpr (N == 12) asm volatile("s_waitcnt vmcnt(12)" ::: "memory");
    else                        asm volatile("s_waitcnt vmcnt(0)" ::: "memory");
}

// ---------------- fp32 -> bf16 convert, all 4 weights in one launch ----------------
#define N4_QKV  786432   // 3072*1024/4
#define N4_WO   262144   // 1024*1024/4
#define N4_FC   1048576  // 4096*1024/4
__global__ __launch_bounds__(256) void cvt_all_kernel(const float* __restrict__ s0,
                                                      const float* __restrict__ s1,
                                                      const float* __restrict__ s2,
                                                      const float* __restrict__ s3,
                                                      u16* __restrict__ dst) {
    int i = blockIdx.x * 256 + threadIdx.x;
    const float* src; int j;
    if (i < N4_QKV)                    { src = s0; j = i; }
    else if (i < N4_QKV + N4_WO)       { src = s1; j = i - N4_QKV; }
    else if (i < N4_QKV + N4_WO + N4_FC) { src = s2; j = i - N4_QKV - N4_WO; }
    else                               { src = s3; j = i - N4_QKV - N4_WO - N4_FC; }
    float4 v = ((const float4*)src)[j];
    ushort4 o;
    o.x = f2bf(v.x); o.y = f2bf(v.y); o.z = f2bf(v.z); o.w = f2bf(v.w);
    ((ushort4*)dst)[i] = o;
}

// ---------------- LayerNorm: fp32 in -> bf16 out ----------------
__global__ __launch_bounds__(256) void ln_kernel(const float* __restrict__ x,
                                                 const float* __restrict__ scale,
                                                 const float* __restrict__ bias,
                                                 u16* __restrict__ out) {
    int row = blockIdx.x;
    int t = threadIdx.x;
    const float* xr = x + (size_t)row * D_MODEL;
    float4 v = ((const float4*)xr)[t];
    float s  = v.x + v.y + v.z + v.w;
    float ss = v.x*v.x + v.y*v.y + v.z*v.z + v.w*v.w;
    #pragma unroll
    for (int off = 1; off < 64; off <<= 1) {
        s  += __shfl_xor(s, off);
        ss += __shfl_xor(ss, off);
    }
    __shared__ float red[8];
    int wave = t >> 6, lane = t & 63;
    if (lane == 0) { red[wave] = s; red[4 + wave] = ss; }
    __syncthreads();
    float S  = red[0] + red[1] + red[2] + red[3];
    float SS = red[4] + red[5] + red[6] + red[7];
    float mu  = S * (1.0f / D_MODEL);
    float var = SS * (1.0f / D_MODEL) - mu * mu;
    float r = rsqrtf(var + 1e-5f);
    float4 sc = ((const float4*)scale)[t];
    float4 bi = ((const float4*)bias)[t];
    ushort4 o;
    o.x = f2bf((v.x - mu) * r * sc.x + bi.x);
    o.y = f2bf((v.y - mu) * r * sc.y + bi.y);
    o.z = f2bf((v.z - mu) * r * sc.z + bi.z);
    o.w = f2bf((v.w - mu) * r * sc.w + bi.w);
    ((ushort4*)(out + (size_t)row * D_MODEL))[t] = o;
}

// ---------------- bf16 MFMA GEMM: 256-row tile, D-deep LDS ring, counted vmcnt ----------------
// C[M,N] = A[M,K] * W[N,K]^T + epilogue (MODE semantics as before)
// 8 waves (2 token-rows x 4 col-groups); wave tile 128 x (BN_/4); BK=32.
// Pipeline: while computing K-tile t from ring slot t%D, stage tile t+D-1 into
// slot (t+D-1)%D (held tile t-1: consumed, barrier-separated). One counted
// vmcnt per K-tile ((RA+RB)*(D-2)) -> tile t+1 landed, newest D-2 batches stay
// in flight across barriers (never drained to 0). Tail: clamped dummy staging
// into the dead slot keeps the count uniform (no drain chain).
template<int MODE, int BN_, int NPH, int DEPTH>
__global__ __launch_bounds__(512, 2) void gemm_kernel(
        const u16* __restrict__ A, const u16* __restrict__ W,
        const float* __restrict__ bias, const float* __restrict__ res,
        void* __restrict__ outp, void* __restrict__ out2, int M, int N, int K) {
    constexpr int BM = 256, BK = 32;
    constexpr int NFN = BN_ / 64;          // N-frags per wave: 4 (BN=256) or 2 (BN=128)
    constexpr int RA = 2;                  // gl2lds rounds per K-tile for A (256x32x2B / 8KB)
    constexpr int RB = BN_ / 128;          // for B: 2 or 1
    constexpr int S = DEPTH - 1;           // stage lead (K-tiles)
    constexpr int VST = (RA + RB) * (S - 1);
    constexpr int ASZ = BM * BK, BSZ = BN_ * BK;
    __shared__ __attribute__((aligned(16))) u16 As[DEPTH * ASZ];
    __shared__ __attribute__((aligned(16))) u16 Bs[DEPTH * BSZ];

    int t = threadIdx.x;
    int lane = t & 63, w = t >> 6;
    int lc = lane & 15, lr = lane >> 4;
    int nb = N / BN_;
    int bm = blockIdx.x / nb, bn = blockIdx.x % nb;
    int m0 = bm * BM, n0 = bn * BN_;
    int wm = (w >> 2) * 128;               // wave token-row base within tile
    int wn = (w & 3) * (BN_ / 4);          // wave col base within tile
    int cxor = (lr ^ (lc & 3)) * 8;        // swizzled 16B-chunk select (row&3 == lc&3)

    const u16* Abase = A + (size_t)m0 * K;
    const u16* Bbase = W + (size_t)n0 * K;

    // staging descriptors: tile rows of 4 16B-chunks; LDS slot cs holds global
    // chunk cs^(row&3) -> conflict-free swizzled fragment reads
    size_t aoff[RA]; int aldo[RA];
    #pragma unroll
    for (int n = 0; n < RA; ++n) {
        int q = (n * 8 + w) * 64 + lane;
        int row = q >> 2;
        aoff[n] = (size_t)row * K + ((q & 3) ^ (row & 3)) * 8;
        aldo[n] = (n * 8 + w) * 512;
    }
    size_t boff[RB]; int bldo[RB];
    #pragma unroll
    for (int n = 0; n < RB; ++n) {
        int q = (n * 8 + w) * 64 + lane;
        int row = q >> 2;
        boff[n] = (size_t)row * K + ((q & 3) ^ (row & 3)) * 8;
        bldo[n] = (n * 8 + w) * 512;
    }

    const int NT = K / BK;
    // prologue: stage tiles 0..S-1 into slots 0..S-1; tile 0 landed after vwait
    for (int u = 0; u < S; ++u) {
        size_t kk = (size_t)u * BK;
        #pragma unroll
        for (int n = 0; n < RA; ++n) gl2lds16(Abase + aoff[n] + kk, &As[u * ASZ + aldo[n]]);
        #pragma unroll
        for (int n = 0; n < RB; ++n) gl2lds16(Bbase + boff[n] + kk, &Bs[u * BSZ + bldo[n]]);
    }
    vwait<VST>();
    bar();

    f4v acc[8][NFN] = {};
    int cur = 0, sb = S % DEPTH;

    for (int kt = 0; kt < NT; ++kt) {
        const u16* Ab = &As[cur * ASZ];
        const u16* Bb = &Bs[cur * BSZ];
        u16* Asb = &As[sb * ASZ];
        u16* Bsb = &Bs[sb * BSZ];
        int kts = kt + S; if (kts >= NT) kts = NT - 1;   // clamped dummy at tail
        size_t kk = (size_t)kts * BK;

        // ---- phase 0: A-frags + B-frags 0,1 ; stage A(t+S) ----
        s8v af[8];
        #pragma unroll
        for (int i = 0; i < 8; ++i)
            af[i] = *(const s8v*)&Ab[(wm + i * 16 + lc) * BK + cxor];
        s8v b0 = *(const s8v*)&Bb[(wn + lc) * BK + cxor];
        s8v b1 = *(const s8v*)&Bb[(wn + 16 + lc) * BK + cxor];
        #pragma unroll
        for (int n = 0; n < RA; ++n) gl2lds16(Abase + aoff[n] + kk, Asb + aldo[n]);
        if constexpr (NPH == 1) {
            #pragma unroll
            for (int n = 0; n < RB; ++n) gl2lds16(Bbase + boff[n] + kk, Bsb + bldo[n]);
        }
        bar();
        __builtin_amdgcn_s_setprio(1);
        #pragma unroll
        for (int i = 0; i < 8; ++i) {
            if constexpr (MODE == 4) {
                acc[i][0] = __builtin_amdgcn_mfma_f32_16x16x32_bf16(af[i], b0, acc[i][0], 0, 0, 0);
                acc[i][1] = __builtin_amdgcn_mfma_f32_16x16x32_bf16(af[i], b1, acc[i][1], 0, 0, 0);
            } else {  // swapped: D.row = W-col, D.col = token
                acc[i][0] = __builtin_amdgcn_mfma_f32_16x16x32_bf16(b0, af[i], acc[i][0], 0, 0, 0);
                acc[i][1] = __builtin_amdgcn_mfma_f32_16x16x32_bf16(b1, af[i], acc[i][1], 0, 0, 0);
            }
        }
        __builtin_amdgcn_s_setprio(0);
        if constexpr (NPH == 1) vwait<VST>();
        bar();

        if constexpr (NPH == 2) {
            // ---- phase 1: B-frags 2,3 (A reused) ; stage B(t+S) ----
            s8v b2 = *(const s8v*)&Bb[(wn + 32 + lc) * BK + cxor];
            s8v b3 = *(const s8v*)&Bb[(wn + 48 + lc) * BK + cxor];
            #pragma unroll
            for (int n = 0; n < RB; ++n) gl2lds16(Bbase + boff[n] + kk, Bsb + bldo[n]);
            bar();
            __builtin_amdgcn_s_setprio(1);
            #pragma unroll
            for (int i = 0; i < 8; ++i) {
                if constexpr (MODE == 4) {
                    acc[i][2] = __builtin_amdgcn_mfma_f32_16x16x32_bf16(af[i], b2, acc[i][2], 0, 0, 0);
                    acc[i][3] = __builtin_amdgcn_mfma_f32_16x16x32_bf16(af[i], b3, acc[i][3], 0, 0, 0);
                } else {
                    acc[i][2] = __builtin_amdgcn_mfma_f32_16x16x32_bf16(b2, af[i], acc[i][2], 0, 0, 0);
                    acc[i][3] = __builtin_amdgcn_mfma_f32_16x16x32_bf16(b3, af[i], acc[i][3], 0, 0, 0);
                }
            }
            __builtin_amdgcn_s_setprio(0);
            vwait<VST>();
            bar();
        }
        cur = (cur + 1 == DEPTH) ? 0 : cur + 1;
        sb  = (sb + 1 == DEPTH) ? 0 : sb + 1;
    }

    if constexpr (MODE == 4) {
        #pragma unroll
        for (int i = 0; i < 8; ++i) {
            #pragma unroll
            for (int j = 0; j < NFN; ++j) {
                int col = n0 + wn + j * 16 + lc;
                int colbase = n0 + wn + j * 16;   // wave-uniform segment select
                if (colbase < 2048) {
                    float sc = (colbase < 1024) ? QSCALE : 1.0f;
                    #pragma unroll
                    for (int r = 0; r < 4; ++r) {
                        int row = m0 + wm + i * 16 + lr * 4 + r;
                        ((u16*)outp)[(size_t)row * 2048 + col] = f2bf(acc[i][j][r] * sc);
                    }
                } else {
                    // V: write transposed to vt[bh*64+d][t], 4 consecutive t packed
                    int dlin = col - 2048;
                    int h = dlin >> 6, dd = dlin & 63;
                    int trow = m0 + wm + i * 16 + lr * 4;
                    int bb = trow >> 11, tt = trow & 2047;
                    int bh = bb * 16 + h;
                    ushort4 vv;
                    vv.x = f2bf(acc[i][j][0]); vv.y = f2bf(acc[i][j][1]);
                    vv.z = f2bf(acc[i][j][2]); vv.w = f2bf(acc[i][j][3]);
                    *(ushort4*)&((u16*)out2)[((size_t)bh * 64 + dd) * SEQ + tt] = vv;
                }
            }
        }
    } else {
        // swapped layout: lane lc owns row = wm+i*16+lc, 4 consecutive cols at lr*4
        #pragma unroll
        for (int j = 0; j < NFN; ++j) {
            int colb = n0 + wn + j * 16 + lr * 4;
            float4 b4;
            if constexpr (MODE != 1) b4 = *(const float4*)&bias[colb];
            #pragma unroll
            for (int i = 0; i < 8; ++i) {
                int row = m0 + wm + i * 16 + lc;
                size_t idx = (size_t)row * N + colb;
                f4v a = acc[i][j];
                if constexpr (MODE == 2) {
                    ushort4 o;
                    o.x = f2bf(gelu_fast(a[0] + b4.x));
                    o.y = f2bf(gelu_fast(a[1] + b4.y));
                    o.z = f2bf(gelu_fast(a[2] + b4.z));
                    o.w = f2bf(gelu_fast(a[3] + b4.w));
                    *(ushort4*)&((u16*)outp)[idx] = o;
                } else {
                    float4 rr = *(const float4*)&res[idx];
                    float4 o;
                    if constexpr (MODE == 3) {
                        o.x = rr.x + a[0] + b4.x; o.y = rr.y + a[1] + b4.y;
                        o.z = rr.z + a[2] + b4.z; o.w = rr.w + a[3] + b4.w;
                    } else {
                        o.x = rr.x + a[0]; o.y = rr.y + a[1];
                        o.z = rr.z + a[2]; o.w = rr.w + a[3];
                    }
                    *(float4*)&((float*)outp)[idx] = o;
                }
            }
        }
    }
}

// ---------------- flash attention, 32x32x16 MFMA (unchanged) ----------------
__global__ __launch_bounds__(256) void attn_kernel(const u16* __restrict__ qk,
                                                   const u16* __restrict__ vt,
                                                   u16* __restrict__ out) {
    __shared__ __attribute__((aligned(16))) u16 Ks[64 * 64];   // [key][d], swizzled chunks
    __shared__ __attribute__((aligned(16))) u16 Vts[64 * 64];  // [d][key], swizzled chunks
    __shared__ __attribute__((aligned(16))) u16 Ps[128 * 68];  // [q][key], stride 68
    __shared__ float l_s[128];
    int t = threadIdx.x, lane = t & 63, w = t >> 6;
    int l31 = lane & 31, hi = lane >> 5;
    int blk = blockIdx.x;
    int bh = blk & 63, qt = blk >> 6;    // XCD swizzle: same head -> same XCD
    int b = bh >> 4, h = bh & 15;
    size_t tok0 = (size_t)b * SEQ;
    int q0 = qt * 128;

    // Q B-operand frags in registers: B[n=q=l31][k=hi*8+j], 4 d-chunks of 16
    s8v bq[4];
    {
        const u16* qp = qk + (tok0 + q0 + w * 32 + l31) * 2048 + h * 64 + hi * 8;
        #pragma unroll
        for (int dch = 0; dch < 4; ++dch) bq[dch] = *(const s8v*)(qp + dch * 16);
    }
    f16v o[2] = {};
    float lp = 0.f;

    int srow[2], scg[2];
    #pragma unroll
    for (int n = 0; n < 2; ++n) {
        int chunk = (w * 2 + n) * 64 + lane;
        srow[n] = chunk >> 3;
        scg[n]  = ((chunk & 7) ^ (srow[n] & 7)) * 8;
    }
    const u16* vbase = vt + (size_t)bh * 64 * SEQ;
    int prow = (w * 32 + l31) * 68;

    for (int kt = 0; kt < SEQ / 64; ++kt) {
        #pragma unroll
        for (int n = 0; n < 2; ++n) {
            gl2lds16(&qk[(tok0 + kt * 64 + srow[n]) * 2048 + 1024 + h * 64 + scg[n]],
                     &Ks[(w * 2 + n) * 512]);
            gl2lds16(&vbase[(size_t)srow[n] * SEQ + kt * 64 + scg[n]],
                     &Vts[(w * 2 + n) * 512]);
        }
        __syncthreads();

        // S^T = K Q'^T : two 32-key blocks
        f16v s_[2] = {};
        #pragma unroll
        for (int kb = 0; kb < 2; ++kb)
            #pragma unroll
            for (int dch = 0; dch < 4; ++dch) {
                s8v ak = *(const s8v*)&Ks[(kb * 32 + l31) * 64 + ((dch * 2 + hi) ^ (l31 & 7)) * 8];
                s_[kb] = __builtin_amdgcn_mfma_f32_32x32x16_bf16(ak, bq[dch], s_[kb], 0, 0, 0);
            }

        #pragma unroll
        for (int kb = 0; kb < 2; ++kb)
            #pragma unroll
            for (int g = 0; g < 4; ++g) {
                u32 ib[4];
                #pragma unroll
                for (int rr = 0; rr < 4; ++rr) {
                    ib[rr] = (u32)fmaf(s_[kb][g * 4 + rr], 8388608.0f, 1064992506.0f);
                    lp += __builtin_bit_cast(float, ib[rr]);
                }
                uint2 pk;
                pk.x = __builtin_amdgcn_perm(ib[1], ib[0], 0x07060302);
                pk.y = __builtin_amdgcn_perm(ib[3], ib[2], 0x07060302);
                *(uint2*)&Ps[prow + kb * 32 + g * 8 + hi * 4] = pk;
            }

        // O += P V
        #pragma unroll
        for (int ch = 0; ch < 4; ++ch) {
            uint2 u0 = *(const uint2*)&Ps[prow + ch * 16 + hi * 8];
            uint2 u1 = *(const uint2*)&Ps[prow + ch * 16 + hi * 8 + 4];
            u4v tmp; tmp.x = u0.x; tmp.y = u0.y; tmp.z = u1.x; tmp.w = u1.y;
            s8v ap = __builtin_bit_cast(s8v, tmp);
            #pragma unroll
            for (int dblk = 0; dblk < 2; ++dblk) {
                s8v bv = *(const s8v*)&Vts[(dblk * 32 + l31) * 64 + ((ch * 2 + hi) ^ (l31 & 7)) * 8];
                o[dblk] = __builtin_amdgcn_mfma_f32_32x32x16_bf16(ap, bv, o[dblk], 0, 0, 0);
            }
        }
        __syncthreads();   // guard Ks/Vts overwrite by next tile's staging
    }

    lp += __shfl_xor(lp, 32);
    l_s[w * 32 + l31] = 1.0f / lp;
    #pragma unroll
    for (int r = 0; r < 16; ++r) {
        int qrl = (r & 3) + 8 * (r >> 2) + 4 * hi;
        float linv = l_s[w * 32 + qrl];
        size_t row = tok0 + q0 + w * 32 + qrl;
        #pragma unroll
        for (int dblk = 0; dblk < 2; ++dblk)
            out[row * 1024 + h * 64 + dblk * 32 + l31] = f2bf(o[dblk][r] * linv);
    }
}

// ---------------- launch ----------------
extern "C" void kernel_launch(void* const* d_in, const int* in_sizes, int n_in,
                              void* d_out, int out_size, void* d_ws, size_t ws_size,
                              hipStream_t stream) {
    const float* x      = (const float*)d_in[0];
    const float* ln1_s  = (const float*)d_in[1];
    const float* ln1_b  = (const float*)d_in[2];
    const float* qkv_w  = (const float*)d_in[3];
    const float* out_w  = (const float*)d_in[4];
    const float* ln2_s  = (const float*)d_in[5];
    const float* ln2_b  = (const float*)d_in[6];
    const float* fc1_w  = (const float*)d_in[7];
    const float* fc1_b  = (const float*)d_in[8];
    const float* fc2_w  = (const float*)d_in[9];
    const float* fc2_b  = (const float*)d_in[10];
    float* out = (float*)d_out;

    char* ws = (char*)d_ws;
    size_t off = 0;
    auto alloc = [&](size_t bytes) -> void* {
        void* p = ws + off;
        off += (bytes + 255) & ~(size_t)255;
        return p;
    };
    u16* wq  = (u16*)alloc((size_t)3072 * 1024 * 2);   // wq|wo|w1|w2 contiguous
    u16* wo  = (u16*)alloc((size_t)1024 * 1024 * 2);
    u16* w1  = (u16*)alloc((size_t)4096 * 1024 * 2);
    u16* w2  = (u16*)alloc((size_t)1024 * 4096 * 2);
    u16* h1  = (u16*)alloc((size_t)TOKENS * 1024 * 2);   // aliased later as attn_out
    u16* qk  = (u16*)alloc((size_t)TOKENS * 2048 * 2);   // Q' | K ; aliased later as h2
    float* x2 = (float*)alloc((size_t)TOKENS * 1024 * 4);
    u16* g   = (u16*)alloc((size_t)TOKENS * 4096 * 2);
    u16* attn_out = h1;        // h1 dead after QKV GEMM
    u16* h2       = qk;        // qk dead after attention
    u16* vt       = (u16*)x2;  // vt (16MB) dead before x2 (32MB) is written
    (void)wo; (void)w1; (void)w2;

    cvt_all_kernel<<<(N4_QKV + N4_WO + 2 * N4_FC) / 256, 256, 0, stream>>>(
        qkv_w, out_w, fc1_w, fc2_w, wq);

    // LN1
    ln_kernel<<<TOKENS, 256, 0, stream>>>(x, ln1_s, ln1_b, h1);
    // QKV projection: 256x256 tiles, depth-4 ring
    gemm_kernel<4, 256, 2, 4><<<(TOKENS / 256) * (3072 / 256), 512, 0, stream>>>(
        h1, wq, nullptr, nullptr, qk, vt, TOKENS, 3072, 1024);
    // attention
    attn_kernel<<<64 * 16, 256, 0, stream>>>(qk, vt, attn_out);
    // out projection + residual: 256x128 tiles (N=1024 -> 256 blocks), depth-6 ring
    gemm_kernel<1, 128, 1, 6><<<(TOKENS / 256) * (1024 / 128), 512, 0, stream>>>(
        attn_out, wo, nullptr, x, x2, nullptr, TOKENS, 1024, 1024);
    // LN2
    ln_kernel<<<TOKENS, 256, 0, stream>>>(x2, ln2_s, ln2_b, h2);
    // FC1 + bias + fast GELU
    gemm_kernel<2, 256, 2, 4><<<(TOKENS / 256) * (DIMFF / 256), 512, 0, stream>>>(
        h2, w1, fc1_b, nullptr, g, nullptr, TOKENS, DIMFF, 1024);
    // FC2 + bias + residual
    gemm_kernel<3, 128, 1, 6><<<(TOKENS / 256) * (1024 / 128), 512, 0, stream>>>(
        g, w2, fc2_b, x2, out, nullptr, TOKENS, 1024, DIMFF);
}

// Round 2
// 523.854 us; speedup vs baseline: 1.0351x; 1.0351x over previous
//
#include <hip/hip_runtime.h>
#include <hip/hip_bf16.h>
#include <math.h>

typedef unsigned short u16;
typedef unsigned int u32;
typedef short s8v __attribute__((ext_vector_type(8)));   // 8 x bf16 bits (4 VGPRs)
typedef float f4v __attribute__((ext_vector_type(4)));   // 16x16 MFMA accumulator
typedef float f16v __attribute__((ext_vector_type(16))); // 32x32 MFMA accumulator
typedef u32 u4v __attribute__((ext_vector_type(4)));

#define D_MODEL 1024
#define DIMFF   4096
#define SEQ     2048
#define TOKENS  8192   // B*T

// 0.125 (1/sqrt(dh)) * log2(e): folded into Q at the QKV epilogue
#define QSCALE 0.18033688011112042f

static __device__ __forceinline__ u16 f2bf(float f) {
    unsigned int u = __builtin_bit_cast(unsigned int, f);
    unsigned int lsb = (u >> 16) & 1u;
    u += 0x7fffu + lsb;                 // round-to-nearest-even
    return (u16)(u >> 16);
}

static __device__ __forceinline__ float gelu_fast(float z) {
    float z2 = z * z;
    float p  = fmaf(z2, -0.1029472255f, -2.3021867892f);  // -2*log2e*sqrt(2/pi)*{0.044715, 1}
    float e  = __builtin_amdgcn_exp2f(z * p);
    return z * __builtin_amdgcn_rcpf(1.0f + e);
}

// async global->LDS, 16B per lane; lds dest = wave-uniform base + lane*16
static __device__ __forceinline__ void gl2lds16(const u16* g, u16* l) {
    __builtin_amdgcn_global_load_lds(
        (__attribute__((address_space(1))) void*)(void*)g,
        (__attribute__((address_space(3))) void*)l, 16, 0, 0);
}

// raw barrier (no compiler vmcnt(0) drain like __syncthreads) + motion fences
static __device__ __forceinline__ void bar() {
    __builtin_amdgcn_sched_barrier(0);
    asm volatile("" ::: "memory");
    __builtin_amdgcn_s_barrier();
    asm volatile("" ::: "memory");
    __builtin_amdgcn_sched_barrier(0);
}

template<int N> static __device__ __forceinline__ void vwait() {
    if constexpr (N == 8)       asm volatile("s_waitcnt vmcnt(8)" ::: "memory");
    else if constexpr (N == 12) asm volatile("s_waitcnt vmcnt(12)" ::: "memory");
    else                        asm volatile("s_waitcnt vmcnt(0)" ::: "memory");
}

// ---------------- fp32 -> bf16 convert, all 4 weights in one launch ----------------
#define N4_QKV  786432   // 3072*1024/4
#define N4_WO   262144   // 1024*1024/4
#define N4_FC   1048576  // 4096*1024/4
__global__ __launch_bounds__(256) void cvt_all_kernel(const float* __restrict__ s0,
                                                      const float* __restrict__ s1,
                                                      const float* __restrict__ s2,
                                                      const float* __restrict__ s3,
                                                      u16* __restrict__ dst) {
    int i = blockIdx.x * 256 + threadIdx.x;
    const float* src; int j;
    if (i < N4_QKV)                    { src = s0; j = i; }
    else if (i < N4_QKV + N4_WO)       { src = s1; j = i - N4_QKV; }
    else if (i < N4_QKV + N4_WO + N4_FC) { src = s2; j = i - N4_QKV - N4_WO; }
    else                               { src = s3; j = i - N4_QKV - N4_WO - N4_FC; }
    float4 v = ((const float4*)src)[j];
    ushort4 o;
    o.x = f2bf(v.x); o.y = f2bf(v.y); o.z = f2bf(v.z); o.w = f2bf(v.w);
    ((ushort4*)dst)[i] = o;
}

// ---------------- LayerNorm: fp32 in -> bf16 out ----------------
__global__ __launch_bounds__(256) void ln_kernel(const float* __restrict__ x,
                                                 const float* __restrict__ scale,
                                                 const float* __restrict__ bias,
                                                 u16* __restrict__ out) {
    int row = blockIdx.x;
    int t = threadIdx.x;
    const float* xr = x + (size_t)row * D_MODEL;
    float4 v = ((const float4*)xr)[t];
    float s  = v.x + v.y + v.z + v.w;
    float ss = v.x*v.x + v.y*v.y + v.z*v.z + v.w*v.w;
    #pragma unroll
    for (int off = 1; off < 64; off <<= 1) {
        s  += __shfl_xor(s, off);
        ss += __shfl_xor(ss, off);
    }
    __shared__ float red[8];
    int wave = t >> 6, lane = t & 63;
    if (lane == 0) { red[wave] = s; red[4 + wave] = ss; }
    __syncthreads();
    float S  = red[0] + red[1] + red[2] + red[3];
    float SS = red[4] + red[5] + red[6] + red[7];
    float mu  = S * (1.0f / D_MODEL);
    float var = SS * (1.0f / D_MODEL) - mu * mu;
    float r = rsqrtf(var + 1e-5f);
    float4 sc = ((const float4*)scale)[t];
    float4 bi = ((const float4*)bias)[t];
    ushort4 o;
    o.x = f2bf((v.x - mu) * r * sc.x + bi.x);
    o.y = f2bf((v.y - mu) * r * sc.y + bi.y);
    o.z = f2bf((v.z - mu) * r * sc.z + bi.z);
    o.w = f2bf((v.w - mu) * r * sc.w + bi.w);
    ((ushort4*)(out + (size_t)row * D_MODEL))[t] = o;
}

// ---------------- bf16 MFMA GEMM: 256-row tile, D-deep LDS ring, counted vmcnt ----------------
// C[M,N] = A[M,K] * W[N,K]^T + epilogue (MODE semantics as before)
// 8 waves (2 token-rows x 4 col-groups); wave tile 128 x (BN_/4); BK=32.
// LDS swizzle (64B rows, 128B bank space spans TWO rows): 16B slot within the
// 128B group = (row&1)*4 + (chunk ^ ((row>>1)&3)) -> bijective over 8 slots
// within each 16-lane phase group => 2 lanes/bank-quad = conflict-free (m136).
// XCD-chunked block remap: blocks sharing an A-panel land on ONE XCD's L2.
// Pipeline: while computing K-tile t from ring slot t%D, stage tile t+D-1 into
// slot (t+D-1)%D; one counted vmcnt per K-tile ((RA+RB)*(D-2)) -> tile t+1
// landed, newest D-2 batches stay in flight across barriers (never drained).
template<int MODE, int BN_, int NPH, int DEPTH>
__global__ __launch_bounds__(512, 2) void gemm_kernel(
        const u16* __restrict__ A, const u16* __restrict__ W,
        const float* __restrict__ bias, const float* __restrict__ res,
        void* __restrict__ outp, void* __restrict__ out2, int M, int N, int K) {
    constexpr int BM = 256, BK = 32;
    constexpr int NFN = BN_ / 64;          // N-frags per wave: 4 (BN=256) or 2 (BN=128)
    constexpr int RA = 2;                  // gl2lds rounds per K-tile for A (256x32x2B / 8KB)
    constexpr int RB = BN_ / 128;          // for B: 2 or 1
    constexpr int S = DEPTH - 1;           // stage lead (K-tiles)
    constexpr int VST = (RA + RB) * (S - 1);
    constexpr int ASZ = BM * BK, BSZ = BN_ * BK;
    __shared__ __attribute__((aligned(16))) u16 As[DEPTH * ASZ];
    __shared__ __attribute__((aligned(16))) u16 Bs[DEPTH * BSZ];

    int t = threadIdx.x;
    int lane = t & 63, w = t >> 6;
    int lc = lane & 15, lr = lane >> 4;
    int nb = N / BN_;
    // bijective XCD-chunked remap (grid always %8==0): XCD x owns a contiguous
    // logical range -> contiguous bm -> A-panel fetched on exactly one XCD
    int cpx = gridDim.x >> 3;
    int blk = (blockIdx.x & 7) * cpx + (blockIdx.x >> 3);
    int bm = blk / nb, bn = blk % nb;
    int m0 = bm * BM, n0 = bn * BN_;
    int wm = (w >> 2) * 128;               // wave token-row base within tile
    int wn = (w & 3) * (BN_ / 4);          // wave col base within tile
    int cxor = (lr ^ ((lc >> 1) & 3)) * 8; // swizzled 16B-chunk select (uses row bits >=1)

    const u16* Abase = A + (size_t)m0 * K;
    const u16* Bbase = W + (size_t)n0 * K;

    // staging descriptors: tile rows of 4 16B-chunks; LDS chunk-slot c' of row r
    // holds global chunk c' ^ ((r>>1)&3) -> conflict-free swizzled fragment reads
    size_t aoff[RA]; int aldo[RA];
    #pragma unroll
    for (int n = 0; n < RA; ++n) {
        int q = (n * 8 + w) * 64 + lane;
        int row = q >> 2;
        aoff[n] = (size_t)row * K + (((q & 3) ^ ((row >> 1) & 3)) * 8);
        aldo[n] = (n * 8 + w) * 512;
    }
    size_t boff[RB]; int bldo[RB];
    #pragma unroll
    for (int n = 0; n < RB; ++n) {
        int q = (n * 8 + w) * 64 + lane;
        int row = q >> 2;
        boff[n] = (size_t)row * K + (((q & 3) ^ ((row >> 1) & 3)) * 8);
        bldo[n] = (n * 8 + w) * 512;
    }

    const int NT = K / BK;
    // prologue: stage tiles 0..S-1 into slots 0..S-1; tile 0 landed after vwait
    for (int u = 0; u < S; ++u) {
        size_t kk = (size_t)u * BK;
        #pragma unroll
        for (int n = 0; n < RA; ++n) gl2lds16(Abase + aoff[n] + kk, &As[u * ASZ + aldo[n]]);
        #pragma unroll
        for (int n = 0; n < RB; ++n) gl2lds16(Bbase + boff[n] + kk, &Bs[u * BSZ + bldo[n]]);
    }
    vwait<VST>();
    bar();

    f4v acc[8][NFN] = {};
    int cur = 0, sb = S % DEPTH;

    for (int kt = 0; kt < NT; ++kt) {
        const u16* Ab = &As[cur * ASZ];
        const u16* Bb = &Bs[cur * BSZ];
        u16* Asb = &As[sb * ASZ];
        u16* Bsb = &Bs[sb * BSZ];
        int kts = kt + S; if (kts >= NT) kts = NT - 1;   // clamped dummy at tail
        size_t kk = (size_t)kts * BK;

        // ---- phase 0: A-frags + B-frags 0,1 ; stage A(t+S) ----
        s8v af[8];
        #pragma unroll
        for (int i = 0; i < 8; ++i)
            af[i] = *(const s8v*)&Ab[(wm + i * 16 + lc) * BK + cxor];
        s8v b0 = *(const s8v*)&Bb[(wn + lc) * BK + cxor];
        s8v b1 = *(const s8v*)&Bb[(wn + 16 + lc) * BK + cxor];
        #pragma unroll
        for (int n = 0; n < RA; ++n) gl2lds16(Abase + aoff[n] + kk, Asb + aldo[n]);
        if constexpr (NPH == 1) {
            #pragma unroll
            for (int n = 0; n < RB; ++n) gl2lds16(Bbase + boff[n] + kk, Bsb + bldo[n]);
        }
        bar();
        __builtin_amdgcn_s_setprio(1);
        #pragma unroll
        for (int i = 0; i < 8; ++i) {
            if constexpr (MODE == 4) {
                acc[i][0] = __builtin_amdgcn_mfma_f32_16x16x32_bf16(af[i], b0, acc[i][0], 0, 0, 0);
                acc[i][1] = __builtin_amdgcn_mfma_f32_16x16x32_bf16(af[i], b1, acc[i][1], 0, 0, 0);
            } else {  // swapped: D.row = W-col, D.col = token
                acc[i][0] = __builtin_amdgcn_mfma_f32_16x16x32_bf16(b0, af[i], acc[i][0], 0, 0, 0);
                acc[i][1] = __builtin_amdgcn_mfma_f32_16x16x32_bf16(b1, af[i], acc[i][1], 0, 0, 0);
            }
        }
        __builtin_amdgcn_s_setprio(0);
        if constexpr (NPH == 1) vwait<VST>();
        bar();

        if constexpr (NPH == 2) {
            // ---- phase 1: B-frags 2,3 (A reused) ; stage B(t+S) ----
            s8v b2 = *(const s8v*)&Bb[(wn + 32 + lc) * BK + cxor];
            s8v b3 = *(const s8v*)&Bb[(wn + 48 + lc) * BK + cxor];
            #pragma unroll
            for (int n = 0; n < RB; ++n) gl2lds16(Bbase + boff[n] + kk, Bsb + bldo[n]);
            bar();
            __builtin_amdgcn_s_setprio(1);
            #pragma unroll
            for (int i = 0; i < 8; ++i) {
                if constexpr (MODE == 4) {
                    acc[i][2] = __builtin_amdgcn_mfma_f32_16x16x32_bf16(af[i], b2, acc[i][2], 0, 0, 0);
                    acc[i][3] = __builtin_amdgcn_mfma_f32_16x16x32_bf16(af[i], b3, acc[i][3], 0, 0, 0);
                } else {
                    acc[i][2] = __builtin_amdgcn_mfma_f32_16x16x32_bf16(b2, af[i], acc[i][2], 0, 0, 0);
                    acc[i][3] = __builtin_amdgcn_mfma_f32_16x16x32_bf16(b3, af[i], acc[i][3], 0, 0, 0);
                }
            }
            __builtin_amdgcn_s_setprio(0);
            vwait<VST>();
            bar();
        }
        cur = (cur + 1 == DEPTH) ? 0 : cur + 1;
        sb  = (sb + 1 == DEPTH) ? 0 : sb + 1;
    }

    if constexpr (MODE == 4) {
        #pragma unroll
        for (int i = 0; i < 8; ++i) {
            #pragma unroll
            for (int j = 0; j < NFN; ++j) {
                int col = n0 + wn + j * 16 + lc;
                int colbase = n0 + wn + j * 16;   // wave-uniform segment select
                if (colbase < 2048) {
                    float sc = (colbase < 1024) ? QSCALE : 1.0f;
                    #pragma unroll
                    for (int r = 0; r < 4; ++r) {
                        int row = m0 + wm + i * 16 + lr * 4 + r;
                        ((u16*)outp)[(size_t)row * 2048 + col] = f2bf(acc[i][j][r] * sc);
                    }
                } else {
                    // V: write transposed to vt[bh*64+d][t], 4 consecutive t packed
                    int dlin = col - 2048;
                    int h = dlin >> 6, dd = dlin & 63;
                    int trow = m0 + wm + i * 16 + lr * 4;
                    int bb = trow >> 11, tt = trow & 2047;
                    int bh = bb * 16 + h;
                    ushort4 vv;
                    vv.x = f2bf(acc[i][j][0]); vv.y = f2bf(acc[i][j][1]);
                    vv.z = f2bf(acc[i][j][2]); vv.w = f2bf(acc[i][j][3]);
                    *(ushort4*)&((u16*)out2)[((size_t)bh * 64 + dd) * SEQ + tt] = vv;
                }
            }
        }
    } else {
        // swapped layout: lane lc owns row = wm+i*16+lc, 4 consecutive cols at lr*4
        #pragma unroll
        for (int j = 0; j < NFN; ++j) {
            int colb = n0 + wn + j * 16 + lr * 4;
            float4 b4;
            if constexpr (MODE != 1) b4 = *(const float4*)&bias[colb];
            #pragma unroll
            for (int i = 0; i < 8; ++i) {
                int row = m0 + wm + i * 16 + lc;
                size_t idx = (size_t)row * N + colb;
                f4v a = acc[i][j];
                if constexpr (MODE == 2) {
                    ushort4 o;
                    o.x = f2bf(gelu_fast(a[0] + b4.x));
                    o.y = f2bf(gelu_fast(a[1] + b4.y));
                    o.z = f2bf(gelu_fast(a[2] + b4.z));
                    o.w = f2bf(gelu_fast(a[3] + b4.w));
                    *(ushort4*)&((u16*)outp)[idx] = o;
                } else {
                    float4 rr = *(const float4*)&res[idx];
                    float4 o;
                    if constexpr (MODE == 3) {
                        o.x = rr.x + a[0] + b4.x; o.y = rr.y + a[1] + b4.y;
                        o.z = rr.z + a[2] + b4.z; o.w = rr.w + a[3] + b4.w;
                    } else {
                        o.x = rr.x + a[0]; o.y = rr.y + a[1];
                        o.z = rr.z + a[2]; o.w = rr.w + a[3];
                    }
                    *(float4*)&((float*)outp)[idx] = o;
                }
            }
        }
    }
}

// ---------------- flash attention, 32x32x16 MFMA (unchanged) ----------------
__global__ __launch_bounds__(256) void attn_kernel(const u16* __restrict__ qk,
                                                   const u16* __restrict__ vt,
                                                   u16* __restrict__ out) {
    __shared__ __attribute__((aligned(16))) u16 Ks[64 * 64];   // [key][d], swizzled chunks
    __shared__ __attribute__((aligned(16))) u16 Vts[64 * 64];  // [d][key], swizzled chunks
    __shared__ __attribute__((aligned(16))) u16 Ps[128 * 68];  // [q][key], stride 68
    __shared__ float l_s[128];
    int t = threadIdx.x, lane = t & 63, w = t >> 6;
    int l31 = lane & 31, hi = lane >> 5;
    int blk = blockIdx.x;
    int bh = blk & 63, qt = blk >> 6;    // XCD swizzle: same head -> same XCD
    int b = bh >> 4, h = bh & 15;
    size_t tok0 = (size_t)b * SEQ;
    int q0 = qt * 128;

    // Q B-operand frags in registers: B[n=q=l31][k=hi*8+j], 4 d-chunks of 16
    s8v bq[4];
    {
        const u16* qp = qk + (tok0 + q0 + w * 32 + l31) * 2048 + h * 64 + hi * 8;
        #pragma unroll
        for (int dch = 0; dch < 4; ++dch) bq[dch] = *(const s8v*)(qp + dch * 16);
    }
    f16v o[2] = {};
    float lp = 0.f;

    int srow[2], scg[2];
    #pragma unroll
    for (int n = 0; n < 2; ++n) {
        int chunk = (w * 2 + n) * 64 + lane;
        srow[n] = chunk >> 3;
        scg[n]  = ((chunk & 7) ^ (srow[n] & 7)) * 8;
    }
    const u16* vbase = vt + (size_t)bh * 64 * SEQ;
    int prow = (w * 32 + l31) * 68;

    for (int kt = 0; kt < SEQ / 64; ++kt) {
        #pragma unroll
        for (int n = 0; n < 2; ++n) {
            gl2lds16(&qk[(tok0 + kt * 64 + srow[n]) * 2048 + 1024 + h * 64 + scg[n]],
                     &Ks[(w * 2 + n) * 512]);
            gl2lds16(&vbase[(size_t)srow[n] * SEQ + kt * 64 + scg[n]],
                     &Vts[(w * 2 + n) * 512]);
        }
        __syncthreads();

        // S^T = K Q'^T : two 32-key blocks
        f16v s_[2] = {};
        #pragma unroll
        for (int kb = 0; kb < 2; ++kb)
            #pragma unroll
            for (int dch = 0; dch < 4; ++dch) {
                s8v ak = *(const s8v*)&Ks[(kb * 32 + l31) * 64 + ((dch * 2 + hi) ^ (l31 & 7)) * 8];
                s_[kb] = __builtin_amdgcn_mfma_f32_32x32x16_bf16(ak, bq[dch], s_[kb], 0, 0, 0);
            }

        #pragma unroll
        for (int kb = 0; kb < 2; ++kb)
            #pragma unroll
            for (int g = 0; g < 4; ++g) {
                u32 ib[4];
                #pragma unroll
                for (int rr = 0; rr < 4; ++rr) {
                    ib[rr] = (u32)fmaf(s_[kb][g * 4 + rr], 8388608.0f, 1064992506.0f);
                    lp += __builtin_bit_cast(float, ib[rr]);
                }
                uint2 pk;
                pk.x = __builtin_amdgcn_perm(ib[1], ib[0], 0x07060302);
                pk.y = __builtin_amdgcn_perm(ib[3], ib[2], 0x07060302);
                *(uint2*)&Ps[prow + kb * 32 + g * 8 + hi * 4] = pk;
            }

        // O += P V
        #pragma unroll
        for (int ch = 0; ch < 4; ++ch) {
            uint2 u0 = *(const uint2*)&Ps[prow + ch * 16 + hi * 8];
            uint2 u1 = *(const uint2*)&Ps[prow + ch * 16 + hi * 8 + 4];
            u4v tmp; tmp.x = u0.x; tmp.y = u0.y; tmp.z = u1.x; tmp.w = u1.y;
            s8v ap = __builtin_bit_cast(s8v, tmp);
            #pragma unroll
            for (int dblk = 0; dblk < 2; ++dblk) {
                s8v bv = *(const s8v*)&Vts[(dblk * 32 + l31) * 64 + ((ch * 2 + hi) ^ (l31 & 7)) * 8];
                o[dblk] = __builtin_amdgcn_mfma_f32_32x32x16_bf16(ap, bv, o[dblk], 0, 0, 0);
            }
        }
        __syncthreads();   // guard Ks/Vts overwrite by next tile's staging
    }

    lp += __shfl_xor(lp, 32);
    l_s[w * 32 + l31] = 1.0f / lp;
    #pragma unroll
    for (int r = 0; r < 16; ++r) {
        int qrl = (r & 3) + 8 * (r >> 2) + 4 * hi;
        float linv = l_s[w * 32 + qrl];
        size_t row = tok0 + q0 + w * 32 + qrl;
        #pragma unroll
        for (int dblk = 0; dblk < 2; ++dblk)
            out[row * 1024 + h * 64 + dblk * 32 + l31] = f2bf(o[dblk][r] * linv);
    }
}

// ---------------- launch ----------------
extern "C" void kernel_launch(void* const* d_in, const int* in_sizes, int n_in,
                              void* d_out, int out_size, void* d_ws, size_t ws_size,
                              hipStream_t stream) {
    const float* x      = (const float*)d_in[0];
    const float* ln1_s  = (const float*)d_in[1];
    const float* ln1_b  = (const float*)d_in[2];
    const float* qkv_w  = (const float*)d_in[3];
    const float* out_w  = (const float*)d_in[4];
    const float* ln2_s  = (const float*)d_in[5];
    const float* ln2_b  = (const float*)d_in[6];
    const float* fc1_w  = (const float*)d_in[7];
    const float* fc1_b  = (const float*)d_in[8];
    const float* fc2_w  = (const float*)d_in[9];
    const float* fc2_b  = (const float*)d_in[10];
    float* out = (float*)d_out;

    char* ws = (char*)d_ws;
    size_t off = 0;
    auto alloc = [&](size_t bytes) -> void* {
        void* p = ws + off;
        off += (bytes + 255) & ~(size_t)255;
        return p;
    };
    u16* wq  = (u16*)alloc((size_t)3072 * 1024 * 2);   // wq|wo|w1|w2 contiguous
    u16* wo  = (u16*)alloc((size_t)1024 * 1024 * 2);
    u16* w1  = (u16*)alloc((size_t)4096 * 1024 * 2);
    u16* w2  = (u16*)alloc((size_t)1024 * 4096 * 2);
    u16* h1  = (u16*)alloc((size_t)TOKENS * 1024 * 2);   // aliased later as attn_out
    u16* qk  = (u16*)alloc((size_t)TOKENS * 2048 * 2);   // Q' | K ; aliased later as h2
    float* x2 = (float*)alloc((size_t)TOKENS * 1024 * 4);
    u16* g   = (u16*)alloc((size_t)TOKENS * 4096 * 2);
    u16* attn_out = h1;        // h1 dead after QKV GEMM
    u16* h2       = qk;        // qk dead after attention
    u16* vt       = (u16*)x2;  // vt (16MB) dead before x2 (32MB) is written
    (void)wo; (void)w1; (void)w2;

    cvt_all_kernel<<<(N4_QKV + N4_WO + 2 * N4_FC) / 256, 256, 0, stream>>>(
        qkv_w, out_w, fc1_w, fc2_w, wq);

    // LN1
    ln_kernel<<<TOKENS, 256, 0, stream>>>(x, ln1_s, ln1_b, h1);
    // QKV projection: 256x256 tiles, depth-4 ring (grid 384 %8==0)
    gemm_kernel<4, 256, 2, 4><<<(TOKENS / 256) * (3072 / 256), 512, 0, stream>>>(
        h1, wq, nullptr, nullptr, qk, vt, TOKENS, 3072, 1024);
    // attention
    attn_kernel<<<64 * 16, 256, 0, stream>>>(qk, vt, attn_out);
    // out projection + residual: 256x128 tiles, depth-6 ring (grid 256)
    gemm_kernel<1, 128, 1, 6><<<(TOKENS / 256) * (1024 / 128), 512, 0, stream>>>(
        attn_out, wo, nullptr, x, x2, nullptr, TOKENS, 1024, 1024);
    // LN2
    ln_kernel<<<TOKENS, 256, 0, stream>>>(x2, ln2_s, ln2_b, h2);
    // FC1 + bias + fast GELU (grid 512)
    gemm_kernel<2, 256, 2, 4><<<(TOKENS / 256) * (DIMFF / 256), 512, 0, stream>>>(
        h2, w1, fc1_b, nullptr, g, nullptr, TOKENS, DIMFF, 1024);
    // FC2 + bias + residual (grid 256)
    gemm_kernel<3, 128, 1, 6><<<(TOKENS / 256) * (1024 / 128), 512, 0, stream>>>(
        g, w2, fc2_b, x2, out, nullptr, TOKENS, 1024, DIMFF);
}

// Round 3
// 492.100 us; speedup vs baseline: 1.1019x; 1.0645x over previous
//
#include <hip/hip_runtime.h>
#include <hip/hip_bf16.h>
#include <math.h>

typedef unsigned short u16;
typedef unsigned int u32;
typedef short s8v __attribute__((ext_vector_type(8)));   // 8 x bf16 bits (4 VGPRs)
typedef float f4v __attribute__((ext_vector_type(4)));   // 16x16 MFMA accumulator
typedef float f16v __attribute__((ext_vector_type(16))); // 32x32 MFMA accumulator
typedef u32 u4v __attribute__((ext_vector_type(4)));

#define D_MODEL 1024
#define DIMFF   4096
#define SEQ     2048
#define TOKENS  8192   // B*T

// 0.125 (1/sqrt(dh)) * log2(e): folded into Q at the QKV epilogue
#define QSCALE 0.18033688011112042f

static __device__ __forceinline__ u16 f2bf(float f) {
    unsigned int u = __builtin_bit_cast(unsigned int, f);
    unsigned int lsb = (u >> 16) & 1u;
    u += 0x7fffu + lsb;                 // round-to-nearest-even
    return (u16)(u >> 16);
}

static __device__ __forceinline__ float gelu_fast(float z) {
    float z2 = z * z;
    float p  = fmaf(z2, -0.1029472255f, -2.3021867892f);  // -2*log2e*sqrt(2/pi)*{0.044715, 1}
    float e  = __builtin_amdgcn_exp2f(z * p);
    return z * __builtin_amdgcn_rcpf(1.0f + e);
}

// async global->LDS, 16B per lane; lds dest = wave-uniform base + lane*16
static __device__ __forceinline__ void gl2lds16(const u16* g, u16* l) {
    __builtin_amdgcn_global_load_lds(
        (__attribute__((address_space(1))) void*)(void*)g,
        (__attribute__((address_space(3))) void*)l, 16, 0, 0);
}

// raw barrier (no compiler vmcnt(0) drain like __syncthreads) + motion fences
static __device__ __forceinline__ void bar() {
    __builtin_amdgcn_sched_barrier(0);
    asm volatile("" ::: "memory");
    __builtin_amdgcn_s_barrier();
    asm volatile("" ::: "memory");
    __builtin_amdgcn_sched_barrier(0);
}

template<int N> static __device__ __forceinline__ void vwait() {
    if constexpr (N == 4)       asm volatile("s_waitcnt vmcnt(4)" ::: "memory");
    else if constexpr (N == 9)  asm volatile("s_waitcnt vmcnt(9)" ::: "memory");
    else if constexpr (N == 12) asm volatile("s_waitcnt vmcnt(12)" ::: "memory");
    else                        asm volatile("s_waitcnt vmcnt(0)" ::: "memory");
}

// ---------------- fp32 -> bf16 convert, all 4 weights in one launch ----------------
#define N4_QKV  786432   // 3072*1024/4
#define N4_WO   262144   // 1024*1024/4
#define N4_FC   1048576  // 4096*1024/4
__global__ __launch_bounds__(256) void cvt_all_kernel(const float* __restrict__ s0,
                                                      const float* __restrict__ s1,
                                                      const float* __restrict__ s2,
                                                      const float* __restrict__ s3,
                                                      u16* __restrict__ dst) {
    int i = blockIdx.x * 256 + threadIdx.x;
    const float* src; int j;
    if (i < N4_QKV)                    { src = s0; j = i; }
    else if (i < N4_QKV + N4_WO)       { src = s1; j = i - N4_QKV; }
    else if (i < N4_QKV + N4_WO + N4_FC) { src = s2; j = i - N4_QKV - N4_WO; }
    else                               { src = s3; j = i - N4_QKV - N4_WO - N4_FC; }
    float4 v = ((const float4*)src)[j];
    ushort4 o;
    o.x = f2bf(v.x); o.y = f2bf(v.y); o.z = f2bf(v.z); o.w = f2bf(v.w);
    ((ushort4*)dst)[i] = o;
}

// ---------------- LayerNorm: fp32 in -> bf16 out ----------------
__global__ __launch_bounds__(256) void ln_kernel(const float* __restrict__ x,
                                                 const float* __restrict__ scale,
                                                 const float* __restrict__ bias,
                                                 u16* __restrict__ out) {
    int row = blockIdx.x;
    int t = threadIdx.x;
    const float* xr = x + (size_t)row * D_MODEL;
    float4 v = ((const float4*)xr)[t];
    float s  = v.x + v.y + v.z + v.w;
    float ss = v.x*v.x + v.y*v.y + v.z*v.z + v.w*v.w;
    #pragma unroll
    for (int off = 1; off < 64; off <<= 1) {
        s  += __shfl_xor(s, off);
        ss += __shfl_xor(ss, off);
    }
    __shared__ float red[8];
    int wave = t >> 6, lane = t & 63;
    if (lane == 0) { red[wave] = s; red[4 + wave] = ss; }
    __syncthreads();
    float S  = red[0] + red[1] + red[2] + red[3];
    float SS = red[4] + red[5] + red[6] + red[7];
    float mu  = S * (1.0f / D_MODEL);
    float var = SS * (1.0f / D_MODEL) - mu * mu;
    float r = rsqrtf(var + 1e-5f);
    float4 sc = ((const float4*)scale)[t];
    float4 bi = ((const float4*)bias)[t];
    ushort4 o;
    o.x = f2bf((v.x - mu) * r * sc.x + bi.x);
    o.y = f2bf((v.y - mu) * r * sc.y + bi.y);
    o.z = f2bf((v.z - mu) * r * sc.z + bi.z);
    o.w = f2bf((v.w - mu) * r * sc.w + bi.w);
    ((ushort4*)(out + (size_t)row * D_MODEL))[t] = o;
}

// ---------------- bf16 MFMA GEMM: reg-double-buffered K-pipeline ----------------
// C[M,N] = A[M,K] * W[N,K]^T + epilogue (MODE semantics as before)
// 8 waves (2 token-rows x 4 col-groups); wave tile 128 x (BN_/4); BK=32.
// Per K-tile t (ONE barrier): issue ds_reads of tile t+1 into the spare reg
// set; issue gl2lds stage of tile t+S into slot (t-1)%D; MFMA tile t from regs
// loaded last iteration (compiler emits counted lgkmcnt over the 8+NFN newer
// reads) -> LDS drain overlaps the MFMA pipe. vmcnt((S-2)*L) before the
// barrier guarantees tile t+2's staged data landed one full tile before its
// ds_read. Stage slot (t-1)%D was last ds_read two barriers ago -> safe.
// LDS swizzle (conflict-free, verified r2): chunk-slot c' of row r holds
// global chunk c' ^ ((r>>1)&3). XCD-chunked block remap (verified r2).
template<int MODE, int BN_, int DEPTH>
__global__ __launch_bounds__(512, 2) void gemm_kernel(
        const u16* __restrict__ A, const u16* __restrict__ W,
        const float* __restrict__ bias, const float* __restrict__ res,
        void* __restrict__ outp, void* __restrict__ out2, int M, int N, int K) {
    constexpr int BM = 256, BK = 32;
    constexpr int NFN = BN_ / 64;          // N-frags per wave: 4 (BN=256) or 2 (BN=128)
    constexpr int RA = 2;                  // gl2lds rounds per K-tile for A
    constexpr int RB = BN_ / 128;          // for B: 2 or 1
    constexpr int S = DEPTH - 1;           // stage lead (K-tiles)
    constexpr int VST = (S - 2) * (RA + RB);
    constexpr int ASZ = BM * BK, BSZ = BN_ * BK;
    __shared__ __attribute__((aligned(16))) u16 As[DEPTH * ASZ];
    __shared__ __attribute__((aligned(16))) u16 Bs[DEPTH * BSZ];

    int t = threadIdx.x;
    int lane = t & 63, w = t >> 6;
    int lc = lane & 15, lr = lane >> 4;
    int nb = N / BN_;
    // bijective XCD-chunked remap (grid always %8==0)
    int cpx = gridDim.x >> 3;
    int blk = (blockIdx.x & 7) * cpx + (blockIdx.x >> 3);
    int bm = blk / nb, bn = blk % nb;
    int m0 = bm * BM, n0 = bn * BN_;
    int wm = (w >> 2) * 128;               // wave token-row base within tile
    int wn = (w & 3) * (BN_ / 4);          // wave col base within tile
    int cxor = (lr ^ ((lc >> 1) & 3)) * 8; // swizzled 16B-chunk select

    const u16* Abase = A + (size_t)m0 * K;
    const u16* Bbase = W + (size_t)n0 * K;

    size_t aoff[RA]; int aldo[RA];
    #pragma unroll
    for (int n = 0; n < RA; ++n) {
        int q = (n * 8 + w) * 64 + lane;
        int row = q >> 2;
        aoff[n] = (size_t)row * K + (((q & 3) ^ ((row >> 1) & 3)) * 8);
        aldo[n] = (n * 8 + w) * 512;
    }
    size_t boff[RB]; int bldo[RB];
    #pragma unroll
    for (int n = 0; n < RB; ++n) {
        int q = (n * 8 + w) * 64 + lane;
        int row = q >> 2;
        boff[n] = (size_t)row * K + (((q & 3) ^ ((row >> 1) & 3)) * 8);
        bldo[n] = (n * 8 + w) * 512;
    }

    const int NT = K / BK;
    // prologue: stage tiles 0..S-1 into slots 0..S-1; tiles 0,1 landed after vwait
    for (int u = 0; u < S; ++u) {
        size_t kk = (size_t)u * BK;
        #pragma unroll
        for (int n = 0; n < RA; ++n) gl2lds16(Abase + aoff[n] + kk, &As[u * ASZ + aldo[n]]);
        #pragma unroll
        for (int n = 0; n < RB; ++n) gl2lds16(Bbase + boff[n] + kk, &Bs[u * BSZ + bldo[n]]);
    }
    vwait<VST>();
    bar();

    f4v acc[8][NFN] = {};
    s8v afA[8], bA_[NFN], afB[8], bB_[NFN];
    // frags(0) from slot 0
    #pragma unroll
    for (int i = 0; i < 8; ++i)
        afA[i] = *(const s8v*)&As[(wm + i * 16 + lc) * BK + cxor];
    #pragma unroll
    for (int j = 0; j < NFN; ++j)
        bA_[j] = *(const s8v*)&Bs[(wn + j * 16 + lc) * BK + cxor];
    int rs = 1, ss = S;

// per-K-tile step: load frags(T+1) into (AFL,BL); stage tile T+S; MFMA (AFC,BC)
#define GSTEP(T, AFL, BL, AFC, BC)                                            \
    {                                                                         \
        const u16* Ab = &As[rs * ASZ];                                        \
        const u16* Bb = &Bs[rs * BSZ];                                        \
        _Pragma("unroll")                                                     \
        for (int i = 0; i < 8; ++i)                                           \
            AFL[i] = *(const s8v*)&Ab[(wm + i * 16 + lc) * BK + cxor];        \
        _Pragma("unroll")                                                     \
        for (int j = 0; j < NFN; ++j)                                         \
            BL[j] = *(const s8v*)&Bb[(wn + j * 16 + lc) * BK + cxor];         \
        int kts = (T) + S; if (kts > NT - 1) kts = NT - 1;                    \
        size_t kk = (size_t)kts * BK;                                         \
        _Pragma("unroll")                                                     \
        for (int n = 0; n < RA; ++n)                                          \
            gl2lds16(Abase + aoff[n] + kk, &As[ss * ASZ + aldo[n]]);          \
        _Pragma("unroll")                                                     \
        for (int n = 0; n < RB; ++n)                                          \
            gl2lds16(Bbase + boff[n] + kk, &Bs[ss * BSZ + bldo[n]]);          \
        __builtin_amdgcn_s_setprio(1);                                        \
        _Pragma("unroll")                                                     \
        for (int i = 0; i < 8; ++i) {                                         \
            _Pragma("unroll")                                                 \
            for (int j = 0; j < NFN; ++j) {                                   \
                if constexpr (MODE == 4)                                      \
                    acc[i][j] = __builtin_amdgcn_mfma_f32_16x16x32_bf16(AFC[i], BC[j], acc[i][j], 0, 0, 0); \
                else                                                          \
                    acc[i][j] = __builtin_amdgcn_mfma_f32_16x16x32_bf16(BC[j], AFC[i], acc[i][j], 0, 0, 0); \
            }                                                                 \
        }                                                                     \
        __builtin_amdgcn_s_setprio(0);                                        \
        vwait<VST>();                                                         \
        bar();                                                                \
        rs = (rs + 1 == DEPTH) ? 0 : rs + 1;                                  \
        ss = (ss + 1 == DEPTH) ? 0 : ss + 1;                                  \
    }

    for (int kt = 0; kt < NT; kt += 2) {
        GSTEP(kt,     afB, bB_, afA, bA_)
        GSTEP(kt + 1, afA, bA_, afB, bB_)
    }
#undef GSTEP

    if constexpr (MODE == 4) {
        #pragma unroll
        for (int i = 0; i < 8; ++i) {
            #pragma unroll
            for (int j = 0; j < NFN; ++j) {
                int col = n0 + wn + j * 16 + lc;
                int colbase = n0 + wn + j * 16;   // wave-uniform segment select
                if (colbase < 2048) {
                    float sc = (colbase < 1024) ? QSCALE : 1.0f;
                    #pragma unroll
                    for (int r = 0; r < 4; ++r) {
                        int row = m0 + wm + i * 16 + lr * 4 + r;
                        ((u16*)outp)[(size_t)row * 2048 + col] = f2bf(acc[i][j][r] * sc);
                    }
                } else {
                    // V: write transposed to vt[bh*64+d][t], 4 consecutive t packed
                    int dlin = col - 2048;
                    int h = dlin >> 6, dd = dlin & 63;
                    int trow = m0 + wm + i * 16 + lr * 4;
                    int bb = trow >> 11, tt = trow & 2047;
                    int bh = bb * 16 + h;
                    ushort4 vv;
                    vv.x = f2bf(acc[i][j][0]); vv.y = f2bf(acc[i][j][1]);
                    vv.z = f2bf(acc[i][j][2]); vv.w = f2bf(acc[i][j][3]);
                    *(ushort4*)&((u16*)out2)[((size_t)bh * 64 + dd) * SEQ + tt] = vv;
                }
            }
        }
    } else {
        // swapped layout: lane lc owns row = wm+i*16+lc, 4 consecutive cols at lr*4
        #pragma unroll
        for (int j = 0; j < NFN; ++j) {
            int colb = n0 + wn + j * 16 + lr * 4;
            float4 b4;
            if constexpr (MODE != 1) b4 = *(const float4*)&bias[colb];
            #pragma unroll
            for (int i = 0; i < 8; ++i) {
                int row = m0 + wm + i * 16 + lc;
                size_t idx = (size_t)row * N + colb;
                f4v a = acc[i][j];
                if constexpr (MODE == 2) {
                    ushort4 o;
                    o.x = f2bf(gelu_fast(a[0] + b4.x));
                    o.y = f2bf(gelu_fast(a[1] + b4.y));
                    o.z = f2bf(gelu_fast(a[2] + b4.z));
                    o.w = f2bf(gelu_fast(a[3] + b4.w));
                    *(ushort4*)&((u16*)outp)[idx] = o;
                } else {
                    float4 rr = *(const float4*)&res[idx];
                    float4 o;
                    if constexpr (MODE == 3) {
                        o.x = rr.x + a[0] + b4.x; o.y = rr.y + a[1] + b4.y;
                        o.z = rr.z + a[2] + b4.z; o.w = rr.w + a[3] + b4.w;
                    } else {
                        o.x = rr.x + a[0]; o.y = rr.y + a[1];
                        o.z = rr.z + a[2]; o.w = rr.w + a[3];
                    }
                    *(float4*)&((float*)outp)[idx] = o;
                }
            }
        }
    }
}

// ---------------- flash attention, 32x32x16 MFMA (unchanged) ----------------
__global__ __launch_bounds__(256) void attn_kernel(const u16* __restrict__ qk,
                                                   const u16* __restrict__ vt,
                                                   u16* __restrict__ out) {
    __shared__ __attribute__((aligned(16))) u16 Ks[64 * 64];   // [key][d], swizzled chunks
    __shared__ __attribute__((aligned(16))) u16 Vts[64 * 64];  // [d][key], swizzled chunks
    __shared__ __attribute__((aligned(16))) u16 Ps[128 * 68];  // [q][key], stride 68
    __shared__ float l_s[128];
    int t = threadIdx.x, lane = t & 63, w = t >> 6;
    int l31 = lane & 31, hi = lane >> 5;
    int blk = blockIdx.x;
    int bh = blk & 63, qt = blk >> 6;    // XCD swizzle: same head -> same XCD
    int b = bh >> 4, h = bh & 15;
    size_t tok0 = (size_t)b * SEQ;
    int q0 = qt * 128;

    // Q B-operand frags in registers: B[n=q=l31][k=hi*8+j], 4 d-chunks of 16
    s8v bq[4];
    {
        const u16* qp = qk + (tok0 + q0 + w * 32 + l31) * 2048 + h * 64 + hi * 8;
        #pragma unroll
        for (int dch = 0; dch < 4; ++dch) bq[dch] = *(const s8v*)(qp + dch * 16);
    }
    f16v o[2] = {};
    float lp = 0.f;

    int srow[2], scg[2];
    #pragma unroll
    for (int n = 0; n < 2; ++n) {
        int chunk = (w * 2 + n) * 64 + lane;
        srow[n] = chunk >> 3;
        scg[n]  = ((chunk & 7) ^ (srow[n] & 7)) * 8;
    }
    const u16* vbase = vt + (size_t)bh * 64 * SEQ;
    int prow = (w * 32 + l31) * 68;

    for (int kt = 0; kt < SEQ / 64; ++kt) {
        #pragma unroll
        for (int n = 0; n < 2; ++n) {
            gl2lds16(&qk[(tok0 + kt * 64 + srow[n]) * 2048 + 1024 + h * 64 + scg[n]],
                     &Ks[(w * 2 + n) * 512]);
            gl2lds16(&vbase[(size_t)srow[n] * SEQ + kt * 64 + scg[n]],
                     &Vts[(w * 2 + n) * 512]);
        }
        __syncthreads();

        // S^T = K Q'^T : two 32-key blocks
        f16v s_[2] = {};
        #pragma unroll
        for (int kb = 0; kb < 2; ++kb)
            #pragma unroll
            for (int dch = 0; dch < 4; ++dch) {
                s8v ak = *(const s8v*)&Ks[(kb * 32 + l31) * 64 + ((dch * 2 + hi) ^ (l31 & 7)) * 8];
                s_[kb] = __builtin_amdgcn_mfma_f32_32x32x16_bf16(ak, bq[dch], s_[kb], 0, 0, 0);
            }

        #pragma unroll
        for (int kb = 0; kb < 2; ++kb)
            #pragma unroll
            for (int g = 0; g < 4; ++g) {
                u32 ib[4];
                #pragma unroll
                for (int rr = 0; rr < 4; ++rr) {
                    ib[rr] = (u32)fmaf(s_[kb][g * 4 + rr], 8388608.0f, 1064992506.0f);
                    lp += __builtin_bit_cast(float, ib[rr]);
                }
                uint2 pk;
                pk.x = __builtin_amdgcn_perm(ib[1], ib[0], 0x07060302);
                pk.y = __builtin_amdgcn_perm(ib[3], ib[2], 0x07060302);
                *(uint2*)&Ps[prow + kb * 32 + g * 8 + hi * 4] = pk;
            }

        // O += P V
        #pragma unroll
        for (int ch = 0; ch < 4; ++ch) {
            uint2 u0 = *(const uint2*)&Ps[prow + ch * 16 + hi * 8];
            uint2 u1 = *(const uint2*)&Ps[prow + ch * 16 + hi * 8 + 4];
            u4v tmp; tmp.x = u0.x; tmp.y = u0.y; tmp.z = u1.x; tmp.w = u1.y;
            s8v ap = __builtin_bit_cast(s8v, tmp);
            #pragma unroll
            for (int dblk = 0; dblk < 2; ++dblk) {
                s8v bv = *(const s8v*)&Vts[(dblk * 32 + l31) * 64 + ((ch * 2 + hi) ^ (l31 & 7)) * 8];
                o[dblk] = __builtin_amdgcn_mfma_f32_32x32x16_bf16(ap, bv, o[dblk], 0, 0, 0);
            }
        }
        __syncthreads();   // guard Ks/Vts overwrite by next tile's staging
    }

    lp += __shfl_xor(lp, 32);
    l_s[w * 32 + l31] = 1.0f / lp;
    #pragma unroll
    for (int r = 0; r < 16; ++r) {
        int qrl = (r & 3) + 8 * (r >> 2) + 4 * hi;
        float linv = l_s[w * 32 + qrl];
        size_t row = tok0 + q0 + w * 32 + qrl;
        #pragma unroll
        for (int dblk = 0; dblk < 2; ++dblk)
            out[row * 1024 + h * 64 + dblk * 32 + l31] = f2bf(o[dblk][r] * linv);
    }
}

// ---------------- launch ----------------
extern "C" void kernel_launch(void* const* d_in, const int* in_sizes, int n_in,
                              void* d_out, int out_size, void* d_ws, size_t ws_size,
                              hipStream_t stream) {
    const float* x      = (const float*)d_in[0];
    const float* ln1_s  = (const float*)d_in[1];
    const float* ln1_b  = (const float*)d_in[2];
    const float* qkv_w  = (const float*)d_in[3];
    const float* out_w  = (const float*)d_in[4];
    const float* ln2_s  = (const float*)d_in[5];
    const float* ln2_b  = (const float*)d_in[6];
    const float* fc1_w  = (const float*)d_in[7];
    const float* fc1_b  = (const float*)d_in[8];
    const float* fc2_w  = (const float*)d_in[9];
    const float* fc2_b  = (const float*)d_in[10];
    float* out = (float*)d_out;

    char* ws = (char*)d_ws;
    size_t off = 0;
    auto alloc = [&](size_t bytes) -> void* {
        void* p = ws + off;
        off += (bytes + 255) & ~(size_t)255;
        return p;
    };
    u16* wq  = (u16*)alloc((size_t)3072 * 1024 * 2);   // wq|wo|w1|w2 contiguous
    u16* wo  = (u16*)alloc((size_t)1024 * 1024 * 2);
    u16* w1  = (u16*)alloc((size_t)4096 * 1024 * 2);
    u16* w2  = (u16*)alloc((size_t)1024 * 4096 * 2);
    u16* h1  = (u16*)alloc((size_t)TOKENS * 1024 * 2);   // aliased later as attn_out
    u16* qk  = (u16*)alloc((size_t)TOKENS * 2048 * 2);   // Q' | K ; aliased later as h2
    float* x2 = (float*)alloc((size_t)TOKENS * 1024 * 4);
    u16* g   = (u16*)alloc((size_t)TOKENS * 4096 * 2);
    u16* attn_out = h1;        // h1 dead after QKV GEMM
    u16* h2       = qk;        // qk dead after attention
    u16* vt       = (u16*)x2;  // vt (16MB) dead before x2 (32MB) is written
    (void)wo; (void)w1; (void)w2;

    cvt_all_kernel<<<(N4_QKV + N4_WO + 2 * N4_FC) / 256, 256, 0, stream>>>(
        qkv_w, out_w, fc1_w, fc2_w, wq);

    // LN1
    ln_kernel<<<TOKENS, 256, 0, stream>>>(x, ln1_s, ln1_b, h1);
    // QKV projection: 256x256 tiles, depth-4 ring (grid 384)
    gemm_kernel<4, 256, 4><<<(TOKENS / 256) * (3072 / 256), 512, 0, stream>>>(
        h1, wq, nullptr, nullptr, qk, vt, TOKENS, 3072, 1024);
    // attention
    attn_kernel<<<64 * 16, 256, 0, stream>>>(qk, vt, attn_out);
    // out projection + residual: 256x128 tiles, depth-6 ring (grid 256)
    gemm_kernel<1, 128, 6><<<(TOKENS / 256) * (1024 / 128), 512, 0, stream>>>(
        attn_out, wo, nullptr, x, x2, nullptr, TOKENS, 1024, 1024);
    // LN2
    ln_kernel<<<TOKENS, 256, 0, stream>>>(x2, ln2_s, ln2_b, h2);
    // FC1 + bias + fast GELU (grid 512)
    gemm_kernel<2, 256, 4><<<(TOKENS / 256) * (DIMFF / 256), 512, 0, stream>>>(
        h2, w1, fc1_b, nullptr, g, nullptr, TOKENS, DIMFF, 1024);
    // FC2 + bias + residual (grid 256)
    gemm_kernel<3, 128, 6><<<(TOKENS / 256) * (1024 / 128), 512, 0, stream>>>(
        g, w2, fc2_b, x2, out, nullptr, TOKENS, 1024, DIMFF);
}

// Round 4
// 483.550 us; speedup vs baseline: 1.1213x; 1.0177x over previous
//
#include <hip/hip_runtime.h>
#include <hip/hip_bf16.h>
#include <math.h>

typedef unsigned short u16;
typedef unsigned int u32;
typedef short s8v __attribute__((ext_vector_type(8)));   // 8 x bf16 bits (4 VGPRs)
typedef float f4v __attribute__((ext_vector_type(4)));   // 16x16 MFMA accumulator
typedef float f16v __attribute__((ext_vector_type(16))); // 32x32 MFMA accumulator
typedef u32 u4v __attribute__((ext_vector_type(4)));
typedef u32 u2v __attribute__((ext_vector_type(2)));

#define D_MODEL 1024
#define DIMFF   4096
#define SEQ     2048
#define TOKENS  8192   // B*T

// 0.125 (1/sqrt(dh)) * log2(e): folded into Q at the QKV epilogue
#define QSCALE 0.18033688011112042f

static __device__ __forceinline__ u16 f2bf(float f) {
    unsigned int u = __builtin_bit_cast(unsigned int, f);
    unsigned int lsb = (u >> 16) & 1u;
    u += 0x7fffu + lsb;                 // round-to-nearest-even
    return (u16)(u >> 16);
}

static __device__ __forceinline__ float gelu_fast(float z) {
    float z2 = z * z;
    float p  = fmaf(z2, -0.1029472255f, -2.3021867892f);  // -2*log2e*sqrt(2/pi)*{0.044715, 1}
    float e  = __builtin_amdgcn_exp2f(z * p);
    return z * __builtin_amdgcn_rcpf(1.0f + e);
}

// async global->LDS, 16B per lane; lds dest = wave-uniform base + lane*16
static __device__ __forceinline__ void gl2lds16(const u16* g, u16* l) {
    __builtin_amdgcn_global_load_lds(
        (__attribute__((address_space(1))) void*)(void*)g,
        (__attribute__((address_space(3))) void*)l, 16, 0, 0);
}

// raw barrier (no compiler vmcnt(0) drain like __syncthreads) + motion fences
static __device__ __forceinline__ void bar() {
    __builtin_amdgcn_sched_barrier(0);
    asm volatile("" ::: "memory");
    __builtin_amdgcn_s_barrier();
    asm volatile("" ::: "memory");
    __builtin_amdgcn_sched_barrier(0);
}

template<int N> static __device__ __forceinline__ void vwait() {
    if constexpr (N == 4)       asm volatile("s_waitcnt vmcnt(4)" ::: "memory");
    else if constexpr (N == 9)  asm volatile("s_waitcnt vmcnt(9)" ::: "memory");
    else if constexpr (N == 12) asm volatile("s_waitcnt vmcnt(12)" ::: "memory");
    else                        asm volatile("s_waitcnt vmcnt(0)" ::: "memory");
}

// ---------------- fp32 -> bf16 convert, all 4 weights in one launch ----------------
#define N4_QKV  786432   // 3072*1024/4
#define N4_WO   262144   // 1024*1024/4
#define N4_FC   1048576  // 4096*1024/4
__global__ __launch_bounds__(256) void cvt_all_kernel(const float* __restrict__ s0,
                                                      const float* __restrict__ s1,
                                                      const float* __restrict__ s2,
                                                      const float* __restrict__ s3,
                                                      u16* __restrict__ dst) {
    int i = blockIdx.x * 256 + threadIdx.x;
    const float* src; int j;
    if (i < N4_QKV)                    { src = s0; j = i; }
    else if (i < N4_QKV + N4_WO)       { src = s1; j = i - N4_QKV; }
    else if (i < N4_QKV + N4_WO + N4_FC) { src = s2; j = i - N4_QKV - N4_WO; }
    else                               { src = s3; j = i - N4_QKV - N4_WO - N4_FC; }
    float4 v = ((const float4*)src)[j];
    ushort4 o;
    o.x = f2bf(v.x); o.y = f2bf(v.y); o.z = f2bf(v.z); o.w = f2bf(v.w);
    ((ushort4*)dst)[i] = o;
}

// ---------------- LayerNorm: fp32 in -> bf16 out ----------------
__global__ __launch_bounds__(256) void ln_kernel(const float* __restrict__ x,
                                                 const float* __restrict__ scale,
                                                 const float* __restrict__ bias,
                                                 u16* __restrict__ out) {
    int row = blockIdx.x;
    int t = threadIdx.x;
    const float* xr = x + (size_t)row * D_MODEL;
    float4 v = ((const float4*)xr)[t];
    float s  = v.x + v.y + v.z + v.w;
    float ss = v.x*v.x + v.y*v.y + v.z*v.z + v.w*v.w;
    #pragma unroll
    for (int off = 1; off < 64; off <<= 1) {
        s  += __shfl_xor(s, off);
        ss += __shfl_xor(ss, off);
    }
    __shared__ float red[8];
    int wave = t >> 6, lane = t & 63;
    if (lane == 0) { red[wave] = s; red[4 + wave] = ss; }
    __syncthreads();
    float S  = red[0] + red[1] + red[2] + red[3];
    float SS = red[4] + red[5] + red[6] + red[7];
    float mu  = S * (1.0f / D_MODEL);
    float var = SS * (1.0f / D_MODEL) - mu * mu;
    float r = rsqrtf(var + 1e-5f);
    float4 sc = ((const float4*)scale)[t];
    float4 bi = ((const float4*)bias)[t];
    ushort4 o;
    o.x = f2bf((v.x - mu) * r * sc.x + bi.x);
    o.y = f2bf((v.y - mu) * r * sc.y + bi.y);
    o.z = f2bf((v.z - mu) * r * sc.z + bi.z);
    o.w = f2bf((v.w - mu) * r * sc.w + bi.w);
    ((ushort4*)(out + (size_t)row * D_MODEL))[t] = o;
}

// ---------------- bf16 MFMA GEMM: reg-double-buffered K-pipeline (verified r3) ----------------
template<int MODE, int BN_, int DEPTH>
__global__ __launch_bounds__(512, 2) void gemm_kernel(
        const u16* __restrict__ A, const u16* __restrict__ W,
        const float* __restrict__ bias, const float* __restrict__ res,
        void* __restrict__ outp, void* __restrict__ out2, int M, int N, int K) {
    constexpr int BM = 256, BK = 32;
    constexpr int NFN = BN_ / 64;          // N-frags per wave: 4 (BN=256) or 2 (BN=128)
    constexpr int RA = 2;                  // gl2lds rounds per K-tile for A
    constexpr int RB = BN_ / 128;          // for B: 2 or 1
    constexpr int S = DEPTH - 1;           // stage lead (K-tiles)
    constexpr int VST = (S - 2) * (RA + RB);
    constexpr int ASZ = BM * BK, BSZ = BN_ * BK;
    __shared__ __attribute__((aligned(16))) u16 As[DEPTH * ASZ];
    __shared__ __attribute__((aligned(16))) u16 Bs[DEPTH * BSZ];

    int t = threadIdx.x;
    int lane = t & 63, w = t >> 6;
    int lc = lane & 15, lr = lane >> 4;
    int nb = N / BN_;
    // bijective XCD-chunked remap (grid always %8==0)
    int cpx = gridDim.x >> 3;
    int blk = (blockIdx.x & 7) * cpx + (blockIdx.x >> 3);
    int bm = blk / nb, bn = blk % nb;
    int m0 = bm * BM, n0 = bn * BN_;
    int wm = (w >> 2) * 128;               // wave token-row base within tile
    int wn = (w & 3) * (BN_ / 4);          // wave col base within tile
    int cxor = (lr ^ ((lc >> 1) & 3)) * 8; // swizzled 16B-chunk select

    const u16* Abase = A + (size_t)m0 * K;
    const u16* Bbase = W + (size_t)n0 * K;

    size_t aoff[RA]; int aldo[RA];
    #pragma unroll
    for (int n = 0; n < RA; ++n) {
        int q = (n * 8 + w) * 64 + lane;
        int row = q >> 2;
        aoff[n] = (size_t)row * K + (((q & 3) ^ ((row >> 1) & 3)) * 8);
        aldo[n] = (n * 8 + w) * 512;
    }
    size_t boff[RB]; int bldo[RB];
    #pragma unroll
    for (int n = 0; n < RB; ++n) {
        int q = (n * 8 + w) * 64 + lane;
        int row = q >> 2;
        boff[n] = (size_t)row * K + (((q & 3) ^ ((row >> 1) & 3)) * 8);
        bldo[n] = (n * 8 + w) * 512;
    }

    const int NT = K / BK;
    // prologue: stage tiles 0..S-1 into slots 0..S-1
    for (int u = 0; u < S; ++u) {
        size_t kk = (size_t)u * BK;
        #pragma unroll
        for (int n = 0; n < RA; ++n) gl2lds16(Abase + aoff[n] + kk, &As[u * ASZ + aldo[n]]);
        #pragma unroll
        for (int n = 0; n < RB; ++n) gl2lds16(Bbase + boff[n] + kk, &Bs[u * BSZ + bldo[n]]);
    }
    vwait<VST>();
    bar();

    f4v acc[8][NFN] = {};
    s8v afA[8], bA_[NFN], afB[8], bB_[NFN];
    // frags(0) from slot 0
    #pragma unroll
    for (int i = 0; i < 8; ++i)
        afA[i] = *(const s8v*)&As[(wm + i * 16 + lc) * BK + cxor];
    #pragma unroll
    for (int j = 0; j < NFN; ++j)
        bA_[j] = *(const s8v*)&Bs[(wn + j * 16 + lc) * BK + cxor];
    int rs = 1, ss = S;

// per-K-tile step: load frags(T+1) into (AFL,BL); stage tile T+S; MFMA (AFC,BC)
#define GSTEP(T, AFL, BL, AFC, BC)                                            \
    {                                                                         \
        const u16* Ab = &As[rs * ASZ];                                        \
        const u16* Bb = &Bs[rs * BSZ];                                        \
        _Pragma("unroll")                                                     \
        for (int i = 0; i < 8; ++i)                                           \
            AFL[i] = *(const s8v*)&Ab[(wm + i * 16 + lc) * BK + cxor];        \
        _Pragma("unroll")                                                     \
        for (int j = 0; j < NFN; ++j)                                         \
            BL[j] = *(const s8v*)&Bb[(wn + j * 16 + lc) * BK + cxor];         \
        int kts = (T) + S; if (kts > NT - 1) kts = NT - 1;                    \
        size_t kk = (size_t)kts * BK;                                         \
        _Pragma("unroll")                                                     \
        for (int n = 0; n < RA; ++n)                                          \
            gl2lds16(Abase + aoff[n] + kk, &As[ss * ASZ + aldo[n]]);          \
        _Pragma("unroll")                                                     \
        for (int n = 0; n < RB; ++n)                                          \
            gl2lds16(Bbase + boff[n] + kk, &Bs[ss * BSZ + bldo[n]]);          \
        __builtin_amdgcn_s_setprio(1);                                        \
        _Pragma("unroll")                                                     \
        for (int i = 0; i < 8; ++i) {                                         \
            _Pragma("unroll")                                                 \
            for (int j = 0; j < NFN; ++j) {                                   \
                if constexpr (MODE == 4)                                      \
                    acc[i][j] = __builtin_amdgcn_mfma_f32_16x16x32_bf16(AFC[i], BC[j], acc[i][j], 0, 0, 0); \
                else                                                          \
                    acc[i][j] = __builtin_amdgcn_mfma_f32_16x16x32_bf16(BC[j], AFC[i], acc[i][j], 0, 0, 0); \
            }                                                                 \
        }                                                                     \
        __builtin_amdgcn_s_setprio(0);                                        \
        vwait<VST>();                                                         \
        bar();                                                                \
        rs = (rs + 1 == DEPTH) ? 0 : rs + 1;                                  \
        ss = (ss + 1 == DEPTH) ? 0 : ss + 1;                                  \
    }

    for (int kt = 0; kt < NT; kt += 2) {
        GSTEP(kt,     afB, bB_, afA, bA_)
        GSTEP(kt + 1, afA, bA_, afB, bB_)
    }
#undef GSTEP

    if constexpr (MODE == 4) {
        #pragma unroll
        for (int i = 0; i < 8; ++i) {
            #pragma unroll
            for (int j = 0; j < NFN; ++j) {
                int col = n0 + wn + j * 16 + lc;
                int colbase = n0 + wn + j * 16;   // wave-uniform segment select
                if (colbase < 2048) {
                    float sc = (colbase < 1024) ? QSCALE : 1.0f;
                    #pragma unroll
                    for (int r = 0; r < 4; ++r) {
                        int row = m0 + wm + i * 16 + lr * 4 + r;
                        ((u16*)outp)[(size_t)row * 2048 + col] = f2bf(acc[i][j][r] * sc);
                    }
                } else {
                    // V: write transposed to vt[bh*64+d][t], 4 consecutive t packed
                    int dlin = col - 2048;
                    int h = dlin >> 6, dd = dlin & 63;
                    int trow = m0 + wm + i * 16 + lr * 4;
                    int bb = trow >> 11, tt = trow & 2047;
                    int bh = bb * 16 + h;
                    ushort4 vv;
                    vv.x = f2bf(acc[i][j][0]); vv.y = f2bf(acc[i][j][1]);
                    vv.z = f2bf(acc[i][j][2]); vv.w = f2bf(acc[i][j][3]);
                    *(ushort4*)&((u16*)out2)[((size_t)bh * 64 + dd) * SEQ + tt] = vv;
                }
            }
        }
    } else {
        // swapped layout: lane lc owns row = wm+i*16+lc, 4 consecutive cols at lr*4
        #pragma unroll
        for (int j = 0; j < NFN; ++j) {
            int colb = n0 + wn + j * 16 + lr * 4;
            float4 b4;
            if constexpr (MODE != 1) b4 = *(const float4*)&bias[colb];
            #pragma unroll
            for (int i = 0; i < 8; ++i) {
                int row = m0 + wm + i * 16 + lc;
                size_t idx = (size_t)row * N + colb;
                f4v a = acc[i][j];
                if constexpr (MODE == 2) {
                    ushort4 o;
                    o.x = f2bf(gelu_fast(a[0] + b4.x));
                    o.y = f2bf(gelu_fast(a[1] + b4.y));
                    o.z = f2bf(gelu_fast(a[2] + b4.z));
                    o.w = f2bf(gelu_fast(a[3] + b4.w));
                    *(ushort4*)&((u16*)outp)[idx] = o;
                } else {
                    float4 rr = *(const float4*)&res[idx];
                    float4 o;
                    if constexpr (MODE == 3) {
                        o.x = rr.x + a[0] + b4.x; o.y = rr.y + a[1] + b4.y;
                        o.z = rr.z + a[2] + b4.z; o.w = rr.w + a[3] + b4.w;
                    } else {
                        o.x = rr.x + a[0]; o.y = rr.y + a[1];
                        o.z = rr.z + a[2]; o.w = rr.w + a[3];
                    }
                    *(float4*)&((float*)outp)[idx] = o;
                }
            }
        }
    }
}

// ---------------- flash attention, 32x32x16 MFMA ----------------
// P transpose now fully in-register via permlane32_swap (T12): the S^T output
// holds P[q][key] split across lane pair (l31, l31+32); one swap per packed
// word pair yields both A-frag halves for both lanes. Ps LDS buffer GONE ->
// no bank conflicts, LDS 34.3KB -> 16.9KB (occupancy no longer LDS-capped).
__global__ __launch_bounds__(256) void attn_kernel(const u16* __restrict__ qk,
                                                   const u16* __restrict__ vt,
                                                   u16* __restrict__ out) {
    __shared__ __attribute__((aligned(16))) u16 Ks[64 * 64];   // [key][d], swizzled chunks
    __shared__ __attribute__((aligned(16))) u16 Vts[64 * 64];  // [d][key], swizzled chunks
    __shared__ float l_s[128];
    int t = threadIdx.x, lane = t & 63, w = t >> 6;
    int l31 = lane & 31, hi = lane >> 5;
    int blk = blockIdx.x;
    int bh = blk & 63, qt = blk >> 6;    // XCD swizzle: same head -> same XCD
    int b = bh >> 4, h = bh & 15;
    size_t tok0 = (size_t)b * SEQ;
    int q0 = qt * 128;

    // Q B-operand frags in registers: B[n=q=l31][k=hi*8+j], 4 d-chunks of 16
    s8v bq[4];
    {
        const u16* qp = qk + (tok0 + q0 + w * 32 + l31) * 2048 + h * 64 + hi * 8;
        #pragma unroll
        for (int dch = 0; dch < 4; ++dch) bq[dch] = *(const s8v*)(qp + dch * 16);
    }
    f16v o[2] = {};
    float lp = 0.f;

    int srow[2], scg[2];
    #pragma unroll
    for (int n = 0; n < 2; ++n) {
        int chunk = (w * 2 + n) * 64 + lane;
        srow[n] = chunk >> 3;
        scg[n]  = ((chunk & 7) ^ (srow[n] & 7)) * 8;
    }
    const u16* vbase = vt + (size_t)bh * 64 * SEQ;

    for (int kt = 0; kt < SEQ / 64; ++kt) {
        #pragma unroll
        for (int n = 0; n < 2; ++n) {
            gl2lds16(&qk[(tok0 + kt * 64 + srow[n]) * 2048 + 1024 + h * 64 + scg[n]],
                     &Ks[(w * 2 + n) * 512]);
            gl2lds16(&vbase[(size_t)srow[n] * SEQ + kt * 64 + scg[n]],
                     &Vts[(w * 2 + n) * 512]);
        }
        __syncthreads();

        // S^T = K Q'^T : two 32-key blocks; D: lane=q, reg r -> key rr+8g+4hi
        f16v s_[2] = {};
        #pragma unroll
        for (int kb = 0; kb < 2; ++kb)
            #pragma unroll
            for (int dch = 0; dch < 4; ++dch) {
                s8v ak = *(const s8v*)&Ks[(kb * 32 + l31) * 64 + ((dch * 2 + hi) ^ (l31 & 7)) * 8];
                s_[kb] = __builtin_amdgcn_mfma_f32_32x32x16_bf16(ak, bq[dch], s_[kb], 0, 0, 0);
            }

        // p = 2^s (Schraudolph bits) -> packed bf16 pairs in registers:
        // pk[kb][g] = keys {8g+4hi+0,1 | 8g+4hi+2,3} for this lane's hi
        u2v pk[2][4];
        #pragma unroll
        for (int kb = 0; kb < 2; ++kb)
            #pragma unroll
            for (int g = 0; g < 4; ++g) {
                u32 ib[4];
                #pragma unroll
                for (int rr = 0; rr < 4; ++rr) {
                    ib[rr] = (u32)fmaf(s_[kb][g * 4 + rr], 8388608.0f, 1064992506.0f);
                    lp += __builtin_bit_cast(float, ib[rr]);
                }
                pk[kb][g][0] = __builtin_amdgcn_perm(ib[1], ib[0], 0x07060302);
                pk[kb][g][1] = __builtin_amdgcn_perm(ib[3], ib[2], 0x07060302);
            }

        // O += P V : A-frag keys ch*16+hi*8+{0..7}; per ch, 2 permlane32_swap
        // deliver own-g (lo out) and partner-g (hi out) words for both lanes
        #pragma unroll
        for (int ch = 0; ch < 4; ++ch) {
            int kb = ch >> 1, a2 = (ch & 1) * 2;
            u2v sx = __builtin_amdgcn_permlane32_swap(pk[kb][a2][0], pk[kb][a2 + 1][0], false, false);
            u2v sy = __builtin_amdgcn_permlane32_swap(pk[kb][a2][1], pk[kb][a2 + 1][1], false, false);
            u4v tmp; tmp.x = sx[0]; tmp.y = sy[0]; tmp.z = sx[1]; tmp.w = sy[1];
            s8v ap = __builtin_bit_cast(s8v, tmp);
            #pragma unroll
            for (int dblk = 0; dblk < 2; ++dblk) {
                s8v bv = *(const s8v*)&Vts[(dblk * 32 + l31) * 64 + ((ch * 2 + hi) ^ (l31 & 7)) * 8];
                o[dblk] = __builtin_amdgcn_mfma_f32_32x32x16_bf16(ap, bv, o[dblk], 0, 0, 0);
            }
        }
        __syncthreads();   // guard Ks/Vts overwrite by next tile's staging
    }

    lp += __shfl_xor(lp, 32);
    l_s[w * 32 + l31] = 1.0f / lp;
    #pragma unroll
    for (int r = 0; r < 16; ++r) {
        int qrl = (r & 3) + 8 * (r >> 2) + 4 * hi;
        float linv = l_s[w * 32 + qrl];
        size_t row = tok0 + q0 + w * 32 + qrl;
        #pragma unroll
        for (int dblk = 0; dblk < 2; ++dblk)
            out[row * 1024 + h * 64 + dblk * 32 + l31] = f2bf(o[dblk][r] * linv);
    }
}

// ---------------- launch ----------------
extern "C" void kernel_launch(void* const* d_in, const int* in_sizes, int n_in,
                              void* d_out, int out_size, void* d_ws, size_t ws_size,
                              hipStream_t stream) {
    const float* x      = (const float*)d_in[0];
    const float* ln1_s  = (const float*)d_in[1];
    const float* ln1_b  = (const float*)d_in[2];
    const float* qkv_w  = (const float*)d_in[3];
    const float* out_w  = (const float*)d_in[4];
    const float* ln2_s  = (const float*)d_in[5];
    const float* ln2_b  = (const float*)d_in[6];
    const float* fc1_w  = (const float*)d_in[7];
    const float* fc1_b  = (const float*)d_in[8];
    const float* fc2_w  = (const float*)d_in[9];
    const float* fc2_b  = (const float*)d_in[10];
    float* out = (float*)d_out;

    char* ws = (char*)d_ws;
    size_t off = 0;
    auto alloc = [&](size_t bytes) -> void* {
        void* p = ws + off;
        off += (bytes + 255) & ~(size_t)255;
        return p;
    };
    u16* wq  = (u16*)alloc((size_t)3072 * 1024 * 2);   // wq|wo|w1|w2 contiguous
    u16* wo  = (u16*)alloc((size_t)1024 * 1024 * 2);
    u16* w1  = (u16*)alloc((size_t)4096 * 1024 * 2);
    u16* w2  = (u16*)alloc((size_t)1024 * 4096 * 2);
    u16* h1  = (u16*)alloc((size_t)TOKENS * 1024 * 2);   // aliased later as attn_out
    u16* qk  = (u16*)alloc((size_t)TOKENS * 2048 * 2);   // Q' | K ; aliased later as h2
    float* x2 = (float*)alloc((size_t)TOKENS * 1024 * 4);
    u16* g   = (u16*)alloc((size_t)TOKENS * 4096 * 2);
    u16* attn_out = h1;        // h1 dead after QKV GEMM
    u16* h2       = qk;        // qk dead after attention
    u16* vt       = (u16*)x2;  // vt (16MB) dead before x2 (32MB) is written
    (void)wo; (void)w1; (void)w2;

    cvt_all_kernel<<<(N4_QKV + N4_WO + 2 * N4_FC) / 256, 256, 0, stream>>>(
        qkv_w, out_w, fc1_w, fc2_w, wq);

    // LN1
    ln_kernel<<<TOKENS, 256, 0, stream>>>(x, ln1_s, ln1_b, h1);
    // QKV projection: 256x256 tiles, depth-4 ring (grid 384)
    gemm_kernel<4, 256, 4><<<(TOKENS / 256) * (3072 / 256), 512, 0, stream>>>(
        h1, wq, nullptr, nullptr, qk, vt, TOKENS, 3072, 1024);
    // attention
    attn_kernel<<<64 * 16, 256, 0, stream>>>(qk, vt, attn_out);
    // out projection + residual: 256x128 tiles, depth-6 ring (grid 256)
    gemm_kernel<1, 128, 6><<<(TOKENS / 256) * (1024 / 128), 512, 0, stream>>>(
        attn_out, wo, nullptr, x, x2, nullptr, TOKENS, 1024, 1024);
    // LN2
    ln_kernel<<<TOKENS, 256, 0, stream>>>(x2, ln2_s, ln2_b, h2);
    // FC1 + bias + fast GELU (grid 512)
    gemm_kernel<2, 256, 4><<<(TOKENS / 256) * (DIMFF / 256), 512, 0, stream>>>(
        h2, w1, fc1_b, nullptr, g, nullptr, TOKENS, DIMFF, 1024);
    // FC2 + bias + residual (grid 256)
    gemm_kernel<3, 128, 6><<<(TOKENS / 256) * (1024 / 128), 512, 0, stream>>>(
        g, w2, fc2_b, x2, out, nullptr, TOKENS, 1024, DIMFF);
}

// Round 5
// 482.182 us; speedup vs baseline: 1.1245x; 1.0028x over previous
//
#include <hip/hip_runtime.h>
#include <hip/hip_bf16.h>
#include <math.h>

typedef unsigned short u16;
typedef unsigned int u32;
typedef short s8v __attribute__((ext_vector_type(8)));   // 8 x bf16 bits (4 VGPRs)
typedef float f4v __attribute__((ext_vector_type(4)));   // 16x16 MFMA accumulator
typedef float f16v __attribute__((ext_vector_type(16))); // 32x32 MFMA accumulator
typedef u32 u4v __attribute__((ext_vector_type(4)));
typedef u32 u2v __attribute__((ext_vector_type(2)));

#define D_MODEL 1024
#define DIMFF   4096
#define SEQ     2048
#define TOKENS  8192   // B*T

// 0.125 (1/sqrt(dh)) * log2(e): folded into Q at the QKV epilogue
#define QSCALE 0.18033688011112042f

static __device__ __forceinline__ u16 f2bf(float f) {
    unsigned int u = __builtin_bit_cast(unsigned int, f);
    unsigned int lsb = (u >> 16) & 1u;
    u += 0x7fffu + lsb;                 // round-to-nearest-even
    return (u16)(u >> 16);
}

static __device__ __forceinline__ float gelu_fast(float z) {
    float z2 = z * z;
    float p  = fmaf(z2, -0.1029472255f, -2.3021867892f);  // -2*log2e*sqrt(2/pi)*{0.044715, 1}
    float e  = __builtin_amdgcn_exp2f(z * p);
    return z * __builtin_amdgcn_rcpf(1.0f + e);
}

// async global->LDS, 16B per lane; lds dest = wave-uniform base + lane*16
static __device__ __forceinline__ void gl2lds16(const u16* g, u16* l) {
    __builtin_amdgcn_global_load_lds(
        (__attribute__((address_space(1))) void*)(void*)g,
        (__attribute__((address_space(3))) void*)l, 16, 0, 0);
}

// raw barrier (no compiler vmcnt(0) drain like __syncthreads) + motion fences
static __device__ __forceinline__ void bar() {
    __builtin_amdgcn_sched_barrier(0);
    asm volatile("" ::: "memory");
    __builtin_amdgcn_s_barrier();
    asm volatile("" ::: "memory");
    __builtin_amdgcn_sched_barrier(0);
}

template<int N> static __device__ __forceinline__ void vwait() {
    if constexpr (N == 4)       asm volatile("s_waitcnt vmcnt(4)" ::: "memory");
    else if constexpr (N == 9)  asm volatile("s_waitcnt vmcnt(9)" ::: "memory");
    else if constexpr (N == 12) asm volatile("s_waitcnt vmcnt(12)" ::: "memory");
    else                        asm volatile("s_waitcnt vmcnt(0)" ::: "memory");
}

// ---------------- fp32 -> bf16 convert, all 4 weights in one launch ----------------
#define N4_QKV  786432   // 3072*1024/4
#define N4_WO   262144   // 1024*1024/4
#define N4_FC   1048576  // 4096*1024/4
__global__ __launch_bounds__(256) void cvt_all_kernel(const float* __restrict__ s0,
                                                      const float* __restrict__ s1,
                                                      const float* __restrict__ s2,
                                                      const float* __restrict__ s3,
                                                      u16* __restrict__ dst) {
    int i = blockIdx.x * 256 + threadIdx.x;
    const float* src; int j;
    if (i < N4_QKV)                    { src = s0; j = i; }
    else if (i < N4_QKV + N4_WO)       { src = s1; j = i - N4_QKV; }
    else if (i < N4_QKV + N4_WO + N4_FC) { src = s2; j = i - N4_QKV - N4_WO; }
    else                               { src = s3; j = i - N4_QKV - N4_WO - N4_FC; }
    float4 v = ((const float4*)src)[j];
    ushort4 o;
    o.x = f2bf(v.x); o.y = f2bf(v.y); o.z = f2bf(v.z); o.w = f2bf(v.w);
    ((ushort4*)dst)[i] = o;
}

// ---------------- LayerNorm: fp32 in -> bf16 out ----------------
__global__ __launch_bounds__(256) void ln_kernel(const float* __restrict__ x,
                                                 const float* __restrict__ scale,
                                                 const float* __restrict__ bias,
                                                 u16* __restrict__ out) {
    int row = blockIdx.x;
    int t = threadIdx.x;
    const float* xr = x + (size_t)row * D_MODEL;
    float4 v = ((const float4*)xr)[t];
    float s  = v.x + v.y + v.z + v.w;
    float ss = v.x*v.x + v.y*v.y + v.z*v.z + v.w*v.w;
    #pragma unroll
    for (int off = 1; off < 64; off <<= 1) {
        s  += __shfl_xor(s, off);
        ss += __shfl_xor(ss, off);
    }
    __shared__ float red[8];
    int wave = t >> 6, lane = t & 63;
    if (lane == 0) { red[wave] = s; red[4 + wave] = ss; }
    __syncthreads();
    float S  = red[0] + red[1] + red[2] + red[3];
    float SS = red[4] + red[5] + red[6] + red[7];
    float mu  = S * (1.0f / D_MODEL);
    float var = SS * (1.0f / D_MODEL) - mu * mu;
    float r = rsqrtf(var + 1e-5f);
    float4 sc = ((const float4*)scale)[t];
    float4 bi = ((const float4*)bias)[t];
    ushort4 o;
    o.x = f2bf((v.x - mu) * r * sc.x + bi.x);
    o.y = f2bf((v.y - mu) * r * sc.y + bi.y);
    o.z = f2bf((v.z - mu) * r * sc.z + bi.z);
    o.w = f2bf((v.w - mu) * r * sc.w + bi.w);
    ((ushort4*)(out + (size_t)row * D_MODEL))[t] = o;
}

// ---------------- bf16 MFMA GEMM: 256x128 tile, depth-6 ring, reg-dbuf pipeline ----------------
// 8 waves as 4 row-groups x 2 col-groups; wave tile 64x64 -> acc[4][4] (64 f32)
// + 64 frag-dbuf regs: fits the 2-wave/EU budget with large margin (no spill).
// LDS slot 24KB, DEPTH=6 (144KB): stage lead = 3+ iterations (~1000cyc) covers
// L3-miss latency. Invariant: at end of iter t, tile t+2 landed ->
// VST=(S-2)*3=9 (prologue stages 5 tiles=15 loads; vmcnt(9) = tiles 0,1 done).
// 2-D XCD remap: xcd owns bm in {4x..4x+3}; bn-major inside -> concurrent
// window per XCD touches A 2MB + W ~4MB (L2-resident, kills W thrash).
// LDS swizzle (verified r2, conflicts=0): chunk-slot c' of row r holds global
// chunk c' ^ ((r>>1)&3).
template<int MODE, int DEPTH>
__global__ __launch_bounds__(512, 2) void gemm_kernel(
        const u16* __restrict__ A, const u16* __restrict__ W,
        const float* __restrict__ bias, const float* __restrict__ res,
        void* __restrict__ outp, void* __restrict__ out2, int M, int N, int K) {
    constexpr int BM = 256, BN_ = 128, BK = 32;
    constexpr int RA = 2;                  // gl2lds rounds per K-tile for A (16KB/8KB)
    constexpr int RB = 1;                  // for B (8KB/8KB)
    constexpr int S = DEPTH - 1;           // stage lead (K-tiles)
    constexpr int VST = (S - 2) * (RA + RB);
    constexpr int ASZ = BM * BK, BSZ = BN_ * BK;
    __shared__ __attribute__((aligned(16))) u16 As[DEPTH * ASZ];
    __shared__ __attribute__((aligned(16))) u16 Bs[DEPTH * BSZ];

    int t = threadIdx.x;
    int lane = t & 63, w = t >> 6;
    int lc = lane & 15, lr = lane >> 4;
    int nb = N / BN_;
    // 2-D XCD remap: all grids have 32 bm = 8 xcd * 4, nb = cpx/4
    int xcd = blockIdx.x & 7, li = blockIdx.x >> 3;
    int bm = xcd * 4 + (li & 3), bn = li >> 2;
    (void)nb;
    int m0 = bm * BM, n0 = bn * BN_;
    int wm = (w & 3) * 64;                 // wave token-row base within tile
    int wn = (w >> 2) * 64;                // wave col base within tile
    int cxor = (lr ^ ((lc >> 1) & 3)) * 8; // swizzled 16B-chunk select

    const u16* Abase = A + (size_t)m0 * K;
    const u16* Bbase = W + (size_t)n0 * K;

    size_t aoff[RA]; int aldo[RA];
    #pragma unroll
    for (int n = 0; n < RA; ++n) {
        int q = (n * 8 + w) * 64 + lane;
        int row = q >> 2;
        aoff[n] = (size_t)row * K + (((q & 3) ^ ((row >> 1) & 3)) * 8);
        aldo[n] = (n * 8 + w) * 512;
    }
    size_t boff; int bldo;
    {
        int q = w * 64 + lane;
        int row = q >> 2;
        boff = (size_t)row * K + (((q & 3) ^ ((row >> 1) & 3)) * 8);
        bldo = w * 512;
    }

    const int NT = K / BK;
    // prologue: stage tiles 0..S-1 into slots 0..S-1
    for (int u = 0; u < S; ++u) {
        size_t kk = (size_t)u * BK;
        #pragma unroll
        for (int n = 0; n < RA; ++n) gl2lds16(Abase + aoff[n] + kk, &As[u * ASZ + aldo[n]]);
        gl2lds16(Bbase + boff + kk, &Bs[u * BSZ + bldo]);
    }
    vwait<VST>();
    bar();

    f4v acc[4][4] = {};
    s8v afA[4], bA_[4], afB[4], bB_[4];
    // frags(0) from slot 0
    #pragma unroll
    for (int i = 0; i < 4; ++i)
        afA[i] = *(const s8v*)&As[(wm + i * 16 + lc) * BK + cxor];
    #pragma unroll
    for (int j = 0; j < 4; ++j)
        bA_[j] = *(const s8v*)&Bs[(wn + j * 16 + lc) * BK + cxor];
    int rs = 1, ss = S;

// per-K-tile step: load frags(T+1) into (AFL,BL); stage tile T+S; MFMA (AFC,BC)
#define GSTEP(T, AFL, BL, AFC, BC)                                            \
    {                                                                         \
        const u16* Ab = &As[rs * ASZ];                                        \
        const u16* Bb = &Bs[rs * BSZ];                                        \
        _Pragma("unroll")                                                     \
        for (int i = 0; i < 4; ++i)                                           \
            AFL[i] = *(const s8v*)&Ab[(wm + i * 16 + lc) * BK + cxor];        \
        _Pragma("unroll")                                                     \
        for (int j = 0; j < 4; ++j)                                           \
            BL[j] = *(const s8v*)&Bb[(wn + j * 16 + lc) * BK + cxor];         \
        int kts = (T) + S; if (kts > NT - 1) kts = NT - 1;                    \
        size_t kk = (size_t)kts * BK;                                         \
        _Pragma("unroll")                                                     \
        for (int n = 0; n < RA; ++n)                                          \
            gl2lds16(Abase + aoff[n] + kk, &As[ss * ASZ + aldo[n]]);          \
        gl2lds16(Bbase + boff + kk, &Bs[ss * BSZ + bldo]);                    \
        __builtin_amdgcn_s_setprio(1);                                        \
        _Pragma("unroll")                                                     \
        for (int i = 0; i < 4; ++i) {                                         \
            _Pragma("unroll")                                                 \
            for (int j = 0; j < 4; ++j) {                                     \
                if constexpr (MODE == 4)                                      \
                    acc[i][j] = __builtin_amdgcn_mfma_f32_16x16x32_bf16(AFC[i], BC[j], acc[i][j], 0, 0, 0); \
                else                                                          \
                    acc[i][j] = __builtin_amdgcn_mfma_f32_16x16x32_bf16(BC[j], AFC[i], acc[i][j], 0, 0, 0); \
            }                                                                 \
        }                                                                     \
        __builtin_amdgcn_s_setprio(0);                                        \
        vwait<VST>();                                                         \
        bar();                                                                \
        rs = (rs + 1 == DEPTH) ? 0 : rs + 1;                                  \
        ss = (ss + 1 == DEPTH) ? 0 : ss + 1;                                  \
    }

    for (int kt = 0; kt < NT; kt += 2) {
        GSTEP(kt,     afB, bB_, afA, bA_)
        GSTEP(kt + 1, afA, bA_, afB, bB_)
    }
#undef GSTEP

    if constexpr (MODE == 4) {
        #pragma unroll
        for (int i = 0; i < 4; ++i) {
            #pragma unroll
            for (int j = 0; j < 4; ++j) {
                int col = n0 + wn + j * 16 + lc;
                int colbase = n0 + wn + j * 16;   // wave-uniform segment select
                if (colbase < 2048) {
                    float sc = (colbase < 1024) ? QSCALE : 1.0f;
                    #pragma unroll
                    for (int r = 0; r < 4; ++r) {
                        int row = m0 + wm + i * 16 + lr * 4 + r;
                        ((u16*)outp)[(size_t)row * 2048 + col] = f2bf(acc[i][j][r] * sc);
                    }
                } else {
                    // V: write transposed to vt[bh*64+d][t], 4 consecutive t packed
                    int dlin = col - 2048;
                    int h = dlin >> 6, dd = dlin & 63;
                    int trow = m0 + wm + i * 16 + lr * 4;
                    int bb = trow >> 11, tt = trow & 2047;
                    int bh = bb * 16 + h;
                    ushort4 vv;
                    vv.x = f2bf(acc[i][j][0]); vv.y = f2bf(acc[i][j][1]);
                    vv.z = f2bf(acc[i][j][2]); vv.w = f2bf(acc[i][j][3]);
                    *(ushort4*)&((u16*)out2)[((size_t)bh * 64 + dd) * SEQ + tt] = vv;
                }
            }
        }
    } else {
        // swapped layout: lane lc owns row = wm+i*16+lc, 4 consecutive cols at lr*4
        #pragma unroll
        for (int j = 0; j < 4; ++j) {
            int colb = n0 + wn + j * 16 + lr * 4;
            float4 b4;
            if constexpr (MODE != 1) b4 = *(const float4*)&bias[colb];
            #pragma unroll
            for (int i = 0; i < 4; ++i) {
                int row = m0 + wm + i * 16 + lc;
                size_t idx = (size_t)row * N + colb;
                f4v a = acc[i][j];
                if constexpr (MODE == 2) {
                    ushort4 o;
                    o.x = f2bf(gelu_fast(a[0] + b4.x));
                    o.y = f2bf(gelu_fast(a[1] + b4.y));
                    o.z = f2bf(gelu_fast(a[2] + b4.z));
                    o.w = f2bf(gelu_fast(a[3] + b4.w));
                    *(ushort4*)&((u16*)outp)[idx] = o;
                } else {
                    float4 rr = *(const float4*)&res[idx];
                    float4 o;
                    if constexpr (MODE == 3) {
                        o.x = rr.x + a[0] + b4.x; o.y = rr.y + a[1] + b4.y;
                        o.z = rr.z + a[2] + b4.z; o.w = rr.w + a[3] + b4.w;
                    } else {
                        o.x = rr.x + a[0]; o.y = rr.y + a[1];
                        o.z = rr.z + a[2]; o.w = rr.w + a[3];
                    }
                    *(float4*)&((float*)outp)[idx] = o;
                }
            }
        }
    }
}

// ---------------- flash attention, 32x32x16 MFMA (unchanged from r4) ----------------
__global__ __launch_bounds__(256) void attn_kernel(const u16* __restrict__ qk,
                                                   const u16* __restrict__ vt,
                                                   u16* __restrict__ out) {
    __shared__ __attribute__((aligned(16))) u16 Ks[64 * 64];   // [key][d], swizzled chunks
    __shared__ __attribute__((aligned(16))) u16 Vts[64 * 64];  // [d][key], swizzled chunks
    __shared__ float l_s[128];
    int t = threadIdx.x, lane = t & 63, w = t >> 6;
    int l31 = lane & 31, hi = lane >> 5;
    int blk = blockIdx.x;
    int bh = blk & 63, qt = blk >> 6;    // XCD swizzle: same head -> same XCD
    int b = bh >> 4, h = bh & 15;
    size_t tok0 = (size_t)b * SEQ;
    int q0 = qt * 128;

    // Q B-operand frags in registers: B[n=q=l31][k=hi*8+j], 4 d-chunks of 16
    s8v bq[4];
    {
        const u16* qp = qk + (tok0 + q0 + w * 32 + l31) * 2048 + h * 64 + hi * 8;
        #pragma unroll
        for (int dch = 0; dch < 4; ++dch) bq[dch] = *(const s8v*)(qp + dch * 16);
    }
    f16v o[2] = {};
    float lp = 0.f;

    int srow[2], scg[2];
    #pragma unroll
    for (int n = 0; n < 2; ++n) {
        int chunk = (w * 2 + n) * 64 + lane;
        srow[n] = chunk >> 3;
        scg[n]  = ((chunk & 7) ^ (srow[n] & 7)) * 8;
    }
    const u16* vbase = vt + (size_t)bh * 64 * SEQ;

    for (int kt = 0; kt < SEQ / 64; ++kt) {
        #pragma unroll
        for (int n = 0; n < 2; ++n) {
            gl2lds16(&qk[(tok0 + kt * 64 + srow[n]) * 2048 + 1024 + h * 64 + scg[n]],
                     &Ks[(w * 2 + n) * 512]);
            gl2lds16(&vbase[(size_t)srow[n] * SEQ + kt * 64 + scg[n]],
                     &Vts[(w * 2 + n) * 512]);
        }
        __syncthreads();

        // S^T = K Q'^T : two 32-key blocks; D: lane=q, reg r -> key rr+8g+4hi
        f16v s_[2] = {};
        #pragma unroll
        for (int kb = 0; kb < 2; ++kb)
            #pragma unroll
            for (int dch = 0; dch < 4; ++dch) {
                s8v ak = *(const s8v*)&Ks[(kb * 32 + l31) * 64 + ((dch * 2 + hi) ^ (l31 & 7)) * 8];
                s_[kb] = __builtin_amdgcn_mfma_f32_32x32x16_bf16(ak, bq[dch], s_[kb], 0, 0, 0);
            }

        // p = 2^s (Schraudolph bits) -> packed bf16 pairs in registers
        u2v pk[2][4];
        #pragma unroll
        for (int kb = 0; kb < 2; ++kb)
            #pragma unroll
            for (int g = 0; g < 4; ++g) {
                u32 ib[4];
                #pragma unroll
                for (int rr = 0; rr < 4; ++rr) {
                    ib[rr] = (u32)fmaf(s_[kb][g * 4 + rr], 8388608.0f, 1064992506.0f);
                    lp += __builtin_bit_cast(float, ib[rr]);
                }
                pk[kb][g][0] = __builtin_amdgcn_perm(ib[1], ib[0], 0x07060302);
                pk[kb][g][1] = __builtin_amdgcn_perm(ib[3], ib[2], 0x07060302);
            }

        // O += P V : per ch, 2 permlane32_swap deliver both A-frag halves
        #pragma unroll
        for (int ch = 0; ch < 4; ++ch) {
            int kb = ch >> 1, a2 = (ch & 1) * 2;
            u2v sx = __builtin_amdgcn_permlane32_swap(pk[kb][a2][0], pk[kb][a2 + 1][0], false, false);
            u2v sy = __builtin_amdgcn_permlane32_swap(pk[kb][a2][1], pk[kb][a2 + 1][1], false, false);
            u4v tmp; tmp.x = sx[0]; tmp.y = sy[0]; tmp.z = sx[1]; tmp.w = sy[1];
            s8v ap = __builtin_bit_cast(s8v, tmp);
            #pragma unroll
            for (int dblk = 0; dblk < 2; ++dblk) {
                s8v bv = *(const s8v*)&Vts[(dblk * 32 + l31) * 64 + ((ch * 2 + hi) ^ (l31 & 7)) * 8];
                o[dblk] = __builtin_amdgcn_mfma_f32_32x32x16_bf16(ap, bv, o[dblk], 0, 0, 0);
            }
        }
        __syncthreads();   // guard Ks/Vts overwrite by next tile's staging
    }

    lp += __shfl_xor(lp, 32);
    l_s[w * 32 + l31] = 1.0f / lp;
    #pragma unroll
    for (int r = 0; r < 16; ++r) {
        int qrl = (r & 3) + 8 * (r >> 2) + 4 * hi;
        float linv = l_s[w * 32 + qrl];
        size_t row = tok0 + q0 + w * 32 + qrl;
        #pragma unroll
        for (int dblk = 0; dblk < 2; ++dblk)
            out[row * 1024 + h * 64 + dblk * 32 + l31] = f2bf(o[dblk][r] * linv);
    }
}

// ---------------- launch ----------------
extern "C" void kernel_launch(void* const* d_in, const int* in_sizes, int n_in,
                              void* d_out, int out_size, void* d_ws, size_t ws_size,
                              hipStream_t stream) {
    const float* x      = (const float*)d_in[0];
    const float* ln1_s  = (const float*)d_in[1];
    const float* ln1_b  = (const float*)d_in[2];
    const float* qkv_w  = (const float*)d_in[3];
    const float* out_w  = (const float*)d_in[4];
    const float* ln2_s  = (const float*)d_in[5];
    const float* ln2_b  = (const float*)d_in[6];
    const float* fc1_w  = (const float*)d_in[7];
    const float* fc1_b  = (const float*)d_in[8];
    const float* fc2_w  = (const float*)d_in[9];
    const float* fc2_b  = (const float*)d_in[10];
    float* out = (float*)d_out;

    char* ws = (char*)d_ws;
    size_t off = 0;
    auto alloc = [&](size_t bytes) -> void* {
        void* p = ws + off;
        off += (bytes + 255) & ~(size_t)255;
        return p;
    };
    u16* wq  = (u16*)alloc((size_t)3072 * 1024 * 2);   // wq|wo|w1|w2 contiguous
    u16* wo  = (u16*)alloc((size_t)1024 * 1024 * 2);
    u16* w1  = (u16*)alloc((size_t)4096 * 1024 * 2);
    u16* w2  = (u16*)alloc((size_t)1024 * 4096 * 2);
    u16* h1  = (u16*)alloc((size_t)TOKENS * 1024 * 2);   // aliased later as attn_out
    u16* qk  = (u16*)alloc((size_t)TOKENS * 2048 * 2);   // Q' | K ; aliased later as h2
    float* x2 = (float*)alloc((size_t)TOKENS * 1024 * 4);
    u16* g   = (u16*)alloc((size_t)TOKENS * 4096 * 2);
    u16* attn_out = h1;        // h1 dead after QKV GEMM
    u16* h2       = qk;        // qk dead after attention
    u16* vt       = (u16*)x2;  // vt (16MB) dead before x2 (32MB) is written
    (void)wo; (void)w1; (void)w2;

    cvt_all_kernel<<<(N4_QKV + N4_WO + 2 * N4_FC) / 256, 256, 0, stream>>>(
        qkv_w, out_w, fc1_w, fc2_w, wq);

    // LN1
    ln_kernel<<<TOKENS, 256, 0, stream>>>(x, ln1_s, ln1_b, h1);
    // QKV projection: 256x128 tiles (grid 768), depth-6 ring
    gemm_kernel<4, 6><<<(TOKENS / 256) * (3072 / 128), 512, 0, stream>>>(
        h1, wq, nullptr, nullptr, qk, vt, TOKENS, 3072, 1024);
    // attention
    attn_kernel<<<64 * 16, 256, 0, stream>>>(qk, vt, attn_out);
    // out projection + residual (grid 256)
    gemm_kernel<1, 6><<<(TOKENS / 256) * (1024 / 128), 512, 0, stream>>>(
        attn_out, wo, nullptr, x, x2, nullptr, TOKENS, 1024, 1024);
    // LN2
    ln_kernel<<<TOKENS, 256, 0, stream>>>(x2, ln2_s, ln2_b, h2);
    // FC1 + bias + fast GELU (grid 1024)
    gemm_kernel<2, 6><<<(TOKENS / 256) * (DIMFF / 128), 512, 0, stream>>>(
        h2, w1, fc1_b, nullptr, g, nullptr, TOKENS, DIMFF, 1024);
    // FC2 + bias + residual (grid 256)
    gemm_kernel<3, 6><<<(TOKENS / 256) * (1024 / 128), 512, 0, stream>>>(
        g, w2, fc2_b, x2, out, nullptr, TOKENS, 1024, DIMFF);
}